// Round 4
// baseline (420.034 us; speedup 1.0000x reference)
//
#include <hip/hip_runtime.h>
#include <stdint.h>

// CAFormer fused block, MI355X gfx950.
// R7: k_attn was latency-bound at 120us (Mfma 11%, VALU 21%, HBM 16%, Occ 21%).
// LDS 54272 -> 40960 (4 blocks/CU instead of 3):
//  - Pls XOR-swizzled [64][256] bf16 (32768 B, no pad)
//  - dir0 PV in 2 col-half passes, Vt staging tile [128][16]u32 = 8192 B
//  - no-max softmax: |S*sc| <= scale = 1 (rows of L2-normalized planes,
//    Cauchy-Schwarz) so exp() is bounded in [1/e, e] -- max-reduce dropped.
// ws layout (160 MiB + 3088 B, proven):
//   qkv bf16 [4][192][65536] @ 0          (100663296 B)
//   oh  bf16 [4][64][65536]  @ 100663296  (33554432 B)
//   ov  bf16                 @ 134217728  (33554432 B)
//   f32 scratch @ 167772160: gxsum[256] cwaw[8] rnorm[512]
// d_out doubles as qkvT bf16 [4][128][65536] between k_tr and k_attn
// (k_conv must stay AFTER k_attn).

typedef unsigned short u16;
typedef __attribute__((ext_vector_type(8))) short bf16x8;
typedef __attribute__((ext_vector_type(4))) float f32x4;

#define DEV static __device__ __forceinline__

DEV u16 f2bf(float f) {
  unsigned u = __float_as_uint(f);
  return (u16)((u + 0x7fffu + ((u >> 16) & 1u)) >> 16);
}
DEV float bf2f(u16 h) { return __uint_as_float(((unsigned)h) << 16); }

// ---------------- gating: per-(b,c) spatial sum of x ----------------
__global__ void k_gx(const float* __restrict__ x, float* __restrict__ gxsum) {
  int bc = blockIdx.x, t = threadIdx.x;
  const float4* p = (const float4*)(x + ((size_t)bc << 16));
  float s = 0.f;
  for (int i = 0; i < 64; ++i) { float4 v = p[t + 256 * i]; s += v.x + v.y + v.z + v.w; }
  for (int off = 32; off; off >>= 1) s += __shfl_down(s, off);
  __shared__ float lds[4];
  if ((t & 63) == 0) lds[t >> 6] = s;
  __syncthreads();
  if (t == 0) gxsum[bc] = lds[0] + lds[1] + lds[2] + lds[3];
}

// ---------------- gating MLP -> cw/aw per batch ----------------
__global__ void k_gate(const float* __restrict__ gxsum, const float* __restrict__ g1w,
                       const float* __restrict__ g1b, const float* __restrict__ g2w,
                       const float* __restrict__ g2b, float* __restrict__ cwaw) {
  __shared__ float h1[4][16];
  int t = threadIdx.x;
  int b = t >> 4, j = t & 15;
  float a = g1b[j];
  for (int c = 0; c < 64; ++c) a += g1w[j * 64 + c] * gxsum[b * 64 + c] * (1.f / 65536.f);
  h1[b][j] = fmaxf(a, 0.f);
  __syncthreads();
  if (t < 4) {
    float l0 = g2b[0], l1 = g2b[1];
    for (int k = 0; k < 16; ++k) { l0 += g2w[k] * h1[t][k]; l1 += g2w[16 + k] * h1[t][k]; }
    float m = fmaxf(l0, l1);
    float e0 = __expf(l0 - m), e1 = __expf(l1 - m);
    float inv = 1.f / (e0 + e1);
    cwaw[t * 2 + 0] = e0 * inv;  // conv weight
    cwaw[t * 2 + 1] = e1 * inv;  // attn weight
  }
}

// ---------------- qkv projection as MFMA GEMM: [192x64] x [64x128px] ----------------
__global__ __launch_bounds__(256) void k_qkv(const float* __restrict__ x,
                                             const float* __restrict__ wqkv,
                                             u16* __restrict__ qkv) {
  __shared__ u16 Ws[192 * 72];  // A: [row][ch], stride 72 shorts
  __shared__ u16 Xs[128 * 72];  // B^T: [px][ch]
  int t = threadIdx.x;
  int b = blockIdx.x >> 9;
  int p0 = (blockIdx.x & 511) << 7;

  // stage wqkv (192x64 fp32 -> bf16)
  {
    int row = t >> 2, c0 = (t & 3) << 4;
#pragma unroll
    for (int i = 0; i < 3; ++i) {
      int r = i * 64 + row;
      const float* src = wqkv + r * 64 + c0;
      unsigned pk[8];
#pragma unroll
      for (int j = 0; j < 8; ++j)
        pk[j] = (unsigned)f2bf(src[2 * j]) | ((unsigned)f2bf(src[2 * j + 1]) << 16);
      uint4* dst = (uint4*)&Ws[r * 72 + c0];
      dst[0] = make_uint4(pk[0], pk[1], pk[2], pk[3]);
      dst[1] = make_uint4(pk[4], pk[5], pk[6], pk[7]);
    }
  }
  // stage x tile: 64ch x 128px, transposed -> Xs[px][ch]
  {
    int p = t & 127, ch = t >> 7;
    const float* xb = x + ((size_t)(b * 64) << 16) + p0 + p;
#pragma unroll
    for (int i = 0; i < 32; ++i) {
      int c = 2 * i + ch;
      Xs[p * 72 + c] = f2bf(xb[(size_t)c << 16]);
    }
  }
  __syncthreads();

  int w = t >> 6, l = t & 63, q = l >> 4, cl = l & 15;
  bf16x8 af[3][2];
#pragma unroll
  for (int g = 0; g < 3; ++g)
#pragma unroll
    for (int k = 0; k < 2; ++k)
      af[g][k] = *(const bf16x8*)&Ws[(w * 48 + g * 16 + cl) * 72 + k * 32 + q * 8];

  f32x4 acc[3][8];
  f32x4 zero = {0.f, 0.f, 0.f, 0.f};
#pragma unroll
  for (int g = 0; g < 3; ++g)
#pragma unroll
    for (int j = 0; j < 8; ++j) acc[g][j] = zero;

  for (int j = 0; j < 8; ++j) {
    bf16x8 b0 = *(const bf16x8*)&Xs[(j * 16 + cl) * 72 + q * 8];
    bf16x8 b1 = *(const bf16x8*)&Xs[(j * 16 + cl) * 72 + 32 + q * 8];
#pragma unroll
    for (int g = 0; g < 3; ++g) {
      acc[g][j] = __builtin_amdgcn_mfma_f32_16x16x32_bf16(af[g][0], b0, acc[g][j], 0, 0, 0);
      acc[g][j] = __builtin_amdgcn_mfma_f32_16x16x32_bf16(af[g][1], b1, acc[g][j], 0, 0, 0);
    }
  }
  u16* outb = qkv + ((size_t)(b * 192) << 16) + p0;
  for (int g = 0; g < 3; ++g) {
    int rowb = w * 48 + g * 16 + q * 4;
#pragma unroll
    for (int r = 0; r < 4; ++r) {
      u16* orow = outb + ((size_t)(rowb + r) << 16);
#pragma unroll
      for (int j = 0; j < 8; ++j) orow[j * 16 + cl] = f2bf(acc[g][j][r]);
    }
  }
}

// ---------------- 1/||plane|| for q,k channels (from bf16 qkv) ----------------
__global__ void k_rnorm(const u16* __restrict__ qkv, float* __restrict__ rnorm) {
  int b = blockIdx.x >> 7, ch = blockIdx.x & 127;
  const uint2* p2 = (const uint2*)(qkv + ((size_t)(b * 192 + ch) << 16));
  int t = threadIdx.x;
  float s = 0.f;
  for (int i = 0; i < 64; ++i) {
    uint2 v = p2[t + 256 * i];
    float a = bf2f(v.x & 0xffff), bq = bf2f(v.x >> 16);
    float c = bf2f(v.y & 0xffff), d = bf2f(v.y >> 16);
    s += a * a + bq * bq + c * c + d * d;
  }
  for (int off = 32; off; off >>= 1) s += __shfl_down(s, off);
  __shared__ float lds[4];
  if ((t & 63) == 0) lds[t >> 6] = s;
  __syncthreads();
  if (t == 0) {
    float tot = lds[0] + lds[1] + lds[2] + lds[3];
    rnorm[blockIdx.x] = 1.f / fmaxf(sqrtf(tot), 1e-12f);
  }
}

// ---------------- transpose Q,K planes (512 planes) into qkvT (= d_out) ----------------
__global__ __launch_bounds__(256) void k_tr(const u16* __restrict__ qkv,
                                            u16* __restrict__ qkvT) {
  int blk = blockIdx.x;
  int tile = blk & 15;
  int pl = blk >> 4;  // b*128 + ch (ch < 128)
  int b = pl >> 7, ch = pl & 127;
  int h0 = (tile >> 2) << 6, w0 = (tile & 3) << 6;
  const u16* ip = qkv + ((size_t)(b * 192 + ch) << 16);
  u16* op = qkvT + ((size_t)pl << 16);
  __shared__ unsigned lds32[64][33];
  int t = threadIdx.x;

  int r = t >> 2, qd = t & 3;
  uint4 v0 = *(const uint4*)&ip[(size_t)(h0 + r) * 256 + w0 + qd * 16];
  uint4 v1 = *(const uint4*)&ip[(size_t)(h0 + r) * 256 + w0 + qd * 16 + 8];
  unsigned vv[8] = {v0.x, v0.y, v0.z, v0.w, v1.x, v1.y, v1.z, v1.w};
#pragma unroll
  for (int k = 0; k < 8; ++k) lds32[r][qd * 8 + k] = vv[k];
  __syncthreads();

  int wl = t >> 2, hq = t & 3;
  unsigned pkout[8];
#pragma unroll
  for (int m = 0; m < 8; ++m) {
    unsigned a = lds32[hq * 16 + 2 * m][wl >> 1];
    unsigned b2 = lds32[hq * 16 + 2 * m + 1][wl >> 1];
    pkout[m] = (wl & 1) ? ((a >> 16) | (b2 & 0xffff0000u))
                        : ((a & 0xffffu) | (b2 << 16));
  }
  *(uint4*)&op[(size_t)(w0 + wl) * 256 + h0 + hq * 16] =
      make_uint4(pkout[0], pkout[1], pkout[2], pkout[3]);
  *(uint4*)&op[(size_t)(w0 + wl) * 256 + h0 + hq * 16 + 8] =
      make_uint4(pkout[4], pkout[5], pkout[6], pkout[7]);
}

// ---------------- depthwise 3x3+5x5 conv, writes cw*conv to d_out (fp32) ----------------
__global__ void k_conv(const float* __restrict__ x, const float* __restrict__ w3,
                       const float* __restrict__ b3, const float* __restrict__ w5,
                       const float* __restrict__ b5, const float* __restrict__ cwaw,
                       float* __restrict__ outmix) {
  int rt = blockIdx.x & 31, bc = blockIdx.x >> 5, c = bc & 63, b = bc >> 6;
  int r0 = rt * 8;
  const float* xp = x + ((size_t)bc << 16);
  __shared__ float xs[12][256];
  int y = threadIdx.x;
  for (int rr = 0; rr < 12; ++rr) {
    int gr = r0 - 2 + rr;
    xs[rr][y] = (gr >= 0 && gr < 256) ? xp[(size_t)gr * 256 + y] : 0.f;
  }
  __syncthreads();
  float W3[9], W5[25];
#pragma unroll
  for (int i = 0; i < 9; ++i) W3[i] = w3[c * 9 + i];
#pragma unroll
  for (int i = 0; i < 25; ++i) W5[i] = w5[c * 25 + i];
  float bias = b3[c] + b5[c];
  float cw = cwaw[b * 2];
  float* op = outmix + ((size_t)bc << 16);
  for (int k = 0; k < 8; ++k) {
    float a = bias;
#pragma unroll
    for (int di = 0; di < 3; ++di)
#pragma unroll
      for (int dj = 0; dj < 3; ++dj) {
        int yy = y + dj - 1;
        float xv = (yy >= 0 && yy < 256) ? xs[k + 1 + di][yy] : 0.f;
        a += W3[di * 3 + dj] * xv;
      }
#pragma unroll
    for (int di = 0; di < 5; ++di)
#pragma unroll
      for (int dj = 0; dj < 5; ++dj) {
        int yy = y + dj - 2;
        float xv = (yy >= 0 && yy < 256) ? xs[k + di][yy] : 0.f;
        a += W5[di * 5 + dj] * xv;
      }
    op[(size_t)(r0 + k) * 256 + y] = cw * a;
  }
}

// ---------------- axial attention, MFMA bf16 ----------------
// dir0: Q,K native rows from qkv; PV in 2 col-half passes, V^T half staged in LDS.
// dir1: Q^T,K^T rows from qkvT (=d_out); V native rows, single PV pass.
__global__ __launch_bounds__(256) void k_attn(
    const u16* __restrict__ qkv, const u16* __restrict__ qkvT,
    const float* __restrict__ rnorm, const float* __restrict__ scale,
    u16* __restrict__ oh, u16* __restrict__ ov) {
  __shared__ __align__(16) unsigned char smem[40960];
  u16* Pls = (u16*)smem;                       // [64][256] bf16, XOR-swizzled (32768 B)
  float* red = (float*)(smem + 32768);         // [4][64] f32 (aliases Vt32, barrier-sep)
  unsigned* Vt32 = (unsigned*)(smem + 32768);  // [128][16] u32 (8192 B, dir0 PV)
  float* Osf = (float*)smem;                   // [32][260] f32 (dir1 store; Pls dead)

  int t = threadIdx.x;
  int w = t >> 6, l = t & 63, q = l >> 4, cl = l & 15;
  // XCD-aware bijective swizzle: 8 consecutive logical blocks (one channel's
  // 4 rt x 2 dir) land on the same XCD -> share planes in that XCD's L2.
  int idx = (blockIdx.x & 7) * 256 + (blockIdx.x >> 3);
  int rt = idx & 3, dir = (idx >> 2) & 1, c = (idx >> 3) & 63, b = idx >> 9;
  int r0 = rt << 6;

  const size_t P = 65536;
  const u16* Qp = dir ? qkvT + (size_t)(b * 128 + c) * P : qkv + (size_t)(b * 192 + c) * P;
  const u16* Kp = dir ? qkvT + (size_t)(b * 128 + 64 + c) * P : qkv + (size_t)(b * 192 + 64 + c) * P;
  const u16* Vp = qkv + (size_t)(b * 192 + 128 + c) * P;  // always native V

  float sc = rnorm[b * 128 + c] * rnorm[b * 128 + 64 + c] * scale[c >> 3];

  f32x4 Sa[4][4];
  f32x4 zero = {0.f, 0.f, 0.f, 0.f};
#pragma unroll
  for (int i = 0; i < 4; ++i)
#pragma unroll
    for (int j = 0; j < 4; ++j) Sa[i][j] = zero;

  // ---- S phase: 8 k-windows of 32, all coalesced bf16x8 row loads ----
  for (int yw = 0; yw < 8; ++yw) {
    int y0 = yw << 5;
    bf16x8 af[4], bfr[4];
#pragma unroll
    for (int i = 0; i < 4; ++i)
      af[i] = *(const bf16x8*)&Qp[(size_t)(r0 + i * 16 + cl) * 256 + y0 + q * 8];
#pragma unroll
    for (int j = 0; j < 4; ++j)
      bfr[j] = *(const bf16x8*)&Kp[(size_t)(w * 64 + j * 16 + cl) * 256 + y0 + q * 8];
#pragma unroll
    for (int i = 0; i < 4; ++i)
#pragma unroll
      for (int j = 0; j < 4; ++j)
        Sa[i][j] = __builtin_amdgcn_mfma_f32_16x16x32_bf16(af[i], bfr[j], Sa[i][j], 0, 0, 0);
  }

  // ---- softmax over cols, NO max pass: |S*sc| <= scale = 1 ----
  float sm[4][4];
#pragma unroll
  for (int i = 0; i < 4; ++i)
#pragma unroll
    for (int r = 0; r < 4; ++r) {
      float s0 = 0.f;
#pragma unroll
      for (int j = 0; j < 4; ++j) {
        float e = __expf(Sa[i][j][r] * sc);
        Sa[i][j][r] = e;
        s0 += e;
      }
#pragma unroll
      for (int off = 1; off < 16; off <<= 1) s0 += __shfl_xor(s0, off);
      sm[i][r] = s0;
    }
  if (cl == 0) {
#pragma unroll
    for (int i = 0; i < 4; ++i)
#pragma unroll
      for (int r = 0; r < 4; ++r) red[w * 64 + i * 16 + q * 4 + r] = sm[i][r];
  }
  __syncthreads();
#pragma unroll
  for (int i = 0; i < 4; ++i)
#pragma unroll
    for (int r = 0; r < 4; ++r) {
      int rho = i * 16 + q * 4 + r;
      sm[i][r] = 1.f / (red[rho] + red[64 + rho] + red[128 + rho] + red[192 + rho]);
    }
  // P -> Pls, XOR-swizzled rows
#pragma unroll
  for (int i = 0; i < 4; ++i)
#pragma unroll
    for (int r = 0; r < 4; ++r) {
      int rho = i * 16 + q * 4 + r;
      int sw = (rho & 7) << 3;
#pragma unroll
      for (int j = 0; j < 4; ++j)
        Pls[(rho * 256 + w * 64 + j * 16 + cl) ^ sw] = f2bf(Sa[i][j][r] * sm[i][r]);
    }
  __syncthreads();  // also separates red reads from Vt32 writes

  // ---- O = P V ----
  if (dir == 0) {
    // 2 passes over col-halves; V^T half tile staged per z-window.
    int cc = t & 15, zp = t >> 4;
    u16* opD = oh + (size_t)(b * 64 + c) * P;
#pragma unroll
    for (int p = 0; p < 2; ++p) {
      f32x4 Oa2[4][2];
#pragma unroll
      for (int i = 0; i < 4; ++i)
#pragma unroll
        for (int jh = 0; jh < 2; ++jh) Oa2[i][jh] = zero;
      for (int zw = 0; zw < 8; ++zw) {
        int z0 = zw << 5;
        const u16* rp = Vp + (size_t)(z0 + 2 * zp) * 256 + p * 128 + cc * 8;
        uint4 a0 = *(const uint4*)rp;
        uint4 a1 = *(const uint4*)(rp + 256);
        unsigned A[4] = {a0.x, a0.y, a0.z, a0.w};
        unsigned Bv[4] = {a1.x, a1.y, a1.z, a1.w};
        __syncthreads();  // previous window's Vt reads complete
#pragma unroll
        for (int m = 0; m < 8; ++m) {
          unsigned lo = (A[m >> 1] >> ((m & 1) * 16)) & 0xffffu;
          unsigned hi = (Bv[m >> 1] >> ((m & 1) * 16)) & 0xffffu;
          int vcol = cc * 8 + m;
          int g = (zp >> 2) ^ ((vcol >> 4) & 3);
          Vt32[vcol * 16 + 4 * g + (zp & 3)] = lo | (hi << 16);
        }
        __syncthreads();
        bf16x8 af[4], bfh[2];
#pragma unroll
        for (int i = 0; i < 4; ++i) {
          int row = i * 16 + cl;
          af[i] = *(const bf16x8*)&Pls[(row * 256 + z0 + q * 8) ^ ((row & 7) << 3)];
        }
#pragma unroll
        for (int jh = 0; jh < 2; ++jh) {
          int vcol = w * 32 + jh * 16 + cl;
          bfh[jh] = *(const bf16x8*)&Vt32[vcol * 16 + 4 * (q ^ ((vcol >> 4) & 3))];
        }
#pragma unroll
        for (int i = 0; i < 4; ++i)
#pragma unroll
          for (int jh = 0; jh < 2; ++jh)
            Oa2[i][jh] = __builtin_amdgcn_mfma_f32_16x16x32_bf16(af[i], bfh[jh], Oa2[i][jh], 0, 0, 0);
      }
#pragma unroll
      for (int i = 0; i < 4; ++i)
#pragma unroll
        for (int jh = 0; jh < 2; ++jh)
#pragma unroll
          for (int r = 0; r < 4; ++r)
            opD[(size_t)(r0 + i * 16 + q * 4 + r) * 256 + p * 128 + w * 32 + jh * 16 + cl] =
                f2bf(Oa2[i][jh][r]);
    }
  } else {
    f32x4 Oa[4][4];
#pragma unroll
    for (int i = 0; i < 4; ++i)
#pragma unroll
      for (int j = 0; j < 4; ++j) Oa[i][j] = zero;
    for (int zw = 0; zw < 8; ++zw) {
      int z0 = zw << 5;
      bf16x8 af[4], bfr[4];
#pragma unroll
      for (int i = 0; i < 4; ++i) {
        int row = i * 16 + cl;
        af[i] = *(const bf16x8*)&Pls[(row * 256 + z0 + q * 8) ^ ((row & 7) << 3)];
      }
#pragma unroll
      for (int j = 0; j < 4; ++j)
        bfr[j] = *(const bf16x8*)&Vp[(size_t)(w * 64 + j * 16 + cl) * 256 + z0 + q * 8];
#pragma unroll
      for (int i = 0; i < 4; ++i)
#pragma unroll
        for (int j = 0; j < 4; ++j)
          Oa[i][j] = __builtin_amdgcn_mfma_f32_16x16x32_bf16(af[i], bfr[j], Oa[i][j], 0, 0, 0);
    }
    // transposed store via LDS (Pls dead; barrier-protected)
    u16* op = ov + (size_t)(b * 64 + c) * P;
    __syncthreads();
    for (int h = 0; h < 2; ++h) {
#pragma unroll
      for (int ii = 0; ii < 2; ++ii) {
        int i = h * 2 + ii;
#pragma unroll
        for (int j = 0; j < 4; ++j)
#pragma unroll
          for (int r = 0; r < 4; ++r)
            Osf[(ii * 16 + q * 4 + r) * 260 + w * 64 + j * 16 + cl] = Oa[i][j][r];
      }
      __syncthreads();
      int rr = t & 31, xb = t >> 5;
      for (int xx = 0; xx < 32; ++xx) {
        int xcol = xx * 8 + xb;
        op[(size_t)xcol * 256 + r0 + h * 32 + rr] = f2bf(Osf[rr * 260 + xcol]);
      }
      __syncthreads();
    }
  }
}

// ---------------- mix + 64x64 projection as MFMA GEMM, in place on d_out ----------------
__global__ __launch_bounds__(256) void k_final(
    float* __restrict__ dout, const u16* __restrict__ oh, const u16* __restrict__ ov,
    const float* __restrict__ wp, const float* __restrict__ bp,
    const float* __restrict__ cwaw) {
  __shared__ u16 Ms[256 * 72];  // B^T: [px][ch]
  __shared__ u16 Ws[64 * 72];   // A: [row][ch]
  int t = threadIdx.x;
  int b = blockIdx.x >> 8;
  int p0 = (blockIdx.x & 255) << 8;
  float aw = cwaw[b * 2 + 1];

  {
    int row = t >> 2, c0 = (t & 3) << 4;
    const float* src = wp + row * 64 + c0;
    unsigned pk[8];
#pragma unroll
    for (int j = 0; j < 8; ++j)
      pk[j] = (unsigned)f2bf(src[2 * j]) | ((unsigned)f2bf(src[2 * j + 1]) << 16);
    uint4* dst = (uint4*)&Ws[row * 72 + c0];
    dst[0] = make_uint4(pk[0], pk[1], pk[2], pk[3]);
    dst[1] = make_uint4(pk[4], pk[5], pk[6], pk[7]);
  }
  {
    size_t base = ((size_t)(b * 64) << 16) + p0 + t;
    for (int c = 0; c < 64; ++c) {
      size_t off = base + ((size_t)c << 16);
      float m = dout[off] + aw * (bf2f(oh[off]) + bf2f(ov[off]));
      Ms[t * 72 + c] = f2bf(m);
    }
  }
  __syncthreads();

  int w = t >> 6, l = t & 63, q = l >> 4, cl = l & 15;
  bf16x8 af0 = *(const bf16x8*)&Ws[(w * 16 + cl) * 72 + q * 8];
  bf16x8 af1 = *(const bf16x8*)&Ws[(w * 16 + cl) * 72 + 32 + q * 8];

  f32x4 acc[16];
  f32x4 zero = {0.f, 0.f, 0.f, 0.f};
#pragma unroll
  for (int j = 0; j < 16; ++j) acc[j] = zero;

  for (int j = 0; j < 16; ++j) {
    bf16x8 b0 = *(const bf16x8*)&Ms[(j * 16 + cl) * 72 + q * 8];
    bf16x8 b1 = *(const bf16x8*)&Ms[(j * 16 + cl) * 72 + 32 + q * 8];
    acc[j] = __builtin_amdgcn_mfma_f32_16x16x32_bf16(af0, b0, acc[j], 0, 0, 0);
    acc[j] = __builtin_amdgcn_mfma_f32_16x16x32_bf16(af1, b1, acc[j], 0, 0, 0);
  }

  float bpv[4];
#pragma unroll
  for (int r = 0; r < 4; ++r) bpv[r] = bp[w * 16 + q * 4 + r];
  float* outb = dout + ((size_t)(b * 64) << 16) + p0;
#pragma unroll
  for (int r = 0; r < 4; ++r) {
    float* orow = outb + ((size_t)(w * 16 + q * 4 + r) << 16);
#pragma unroll
    for (int j = 0; j < 16; ++j) orow[j * 16 + cl] = acc[j][r] + bpv[r];
  }
}

extern "C" void kernel_launch(void* const* d_in, const int* in_sizes, int n_in,
                              void* d_out, int out_size, void* d_ws, size_t ws_size,
                              hipStream_t stream) {
  const float* x = (const float*)d_in[0];
  const float* w3 = (const float*)d_in[1];
  const float* b3 = (const float*)d_in[2];
  const float* w5 = (const float*)d_in[3];
  const float* b5 = (const float*)d_in[4];
  const float* wqkv = (const float*)d_in[5];
  const float* scale = (const float*)d_in[6];
  const float* g1w = (const float*)d_in[7];
  const float* g1b = (const float*)d_in[8];
  const float* g2w = (const float*)d_in[9];
  const float* g2b = (const float*)d_in[10];
  const float* wp = (const float*)d_in[11];
  const float* bp = (const float*)d_in[12];
  float* out = (float*)d_out;

  char* ws = (char*)d_ws;
  u16* qkv = (u16*)(ws);
  u16* ohb = (u16*)(ws + 100663296ull);
  u16* ovb = (u16*)(ws + 134217728ull);
  float* fs = (float*)(ws + 167772160ull);
  float* gxsum = fs;        // 256
  float* cwaw = fs + 256;   // 8
  float* rnorm = fs + 264;  // 512
  u16* qkvT = (u16*)d_out;  // 64 MiB, dead until k_conv overwrites it

  k_gx<<<256, 256, 0, stream>>>(x, gxsum);
  k_gate<<<1, 64, 0, stream>>>(gxsum, g1w, g1b, g2w, g2b, cwaw);
  k_qkv<<<2048, 256, 0, stream>>>(x, wqkv, qkv);
  k_rnorm<<<512, 256, 0, stream>>>(qkv, rnorm);
  k_tr<<<8192, 256, 0, stream>>>(qkv, qkvT);
  k_attn<<<2048, 256, 0, stream>>>(qkv, qkvT, rnorm, scale, ohb, ovb);
  k_conv<<<8192, 256, 0, stream>>>(x, w3, b3, w5, b5, cwaw, out);
  k_final<<<1024, 256, 0, stream>>>(out, ohb, ovb, wp, bp, cwaw);
}

// Round 5
// 418.028 us; speedup vs baseline: 1.0048x; 1.0048x over previous
//
#include <hip/hip_runtime.h>
#include <stdint.h>

// CAFormer fused block, MI355X gfx950.
// R8: R7 failed (VGPR 136 capped waves at 3/SIMD; 2-pass PV added 32 barriers
// -> 180us). Revert to R6's proven dir0 staging + unswizzled Pls, but with
// 32-row tiles (grid 4096): Sa/Oa halved (VGPR<<128, pinned via
// __launch_bounds__(256,4)), LDS 37888 -> 4 blocks/CU = 16 waves/CU.
// Keep R7's no-max softmax (|S*sc| <= scale, plane-L2norm Cauchy-Schwarz).
// ws layout (160 MiB + 3088 B, proven):
//   qkv bf16 [4][192][65536] @ 0          (100663296 B)
//   oh  bf16 [4][64][65536]  @ 100663296  (33554432 B)
//   ov  bf16                 @ 134217728  (33554432 B)
//   f32 scratch @ 167772160: gxsum[256] cwaw[8] rnorm[512]
// d_out doubles as qkvT bf16 [4][128][65536] between k_tr and k_attn
// (k_conv must stay AFTER k_attn).

typedef unsigned short u16;
typedef __attribute__((ext_vector_type(8))) short bf16x8;
typedef __attribute__((ext_vector_type(4))) float f32x4;

#define DEV static __device__ __forceinline__

DEV u16 f2bf(float f) {
  unsigned u = __float_as_uint(f);
  return (u16)((u + 0x7fffu + ((u >> 16) & 1u)) >> 16);
}
DEV float bf2f(u16 h) { return __uint_as_float(((unsigned)h) << 16); }

// ---------------- gating: per-(b,c) spatial sum of x ----------------
__global__ void k_gx(const float* __restrict__ x, float* __restrict__ gxsum) {
  int bc = blockIdx.x, t = threadIdx.x;
  const float4* p = (const float4*)(x + ((size_t)bc << 16));
  float s = 0.f;
  for (int i = 0; i < 64; ++i) { float4 v = p[t + 256 * i]; s += v.x + v.y + v.z + v.w; }
  for (int off = 32; off; off >>= 1) s += __shfl_down(s, off);
  __shared__ float lds[4];
  if ((t & 63) == 0) lds[t >> 6] = s;
  __syncthreads();
  if (t == 0) gxsum[bc] = lds[0] + lds[1] + lds[2] + lds[3];
}

// ---------------- gating MLP -> cw/aw per batch ----------------
__global__ void k_gate(const float* __restrict__ gxsum, const float* __restrict__ g1w,
                       const float* __restrict__ g1b, const float* __restrict__ g2w,
                       const float* __restrict__ g2b, float* __restrict__ cwaw) {
  __shared__ float h1[4][16];
  int t = threadIdx.x;
  int b = t >> 4, j = t & 15;
  float a = g1b[j];
  for (int c = 0; c < 64; ++c) a += g1w[j * 64 + c] * gxsum[b * 64 + c] * (1.f / 65536.f);
  h1[b][j] = fmaxf(a, 0.f);
  __syncthreads();
  if (t < 4) {
    float l0 = g2b[0], l1 = g2b[1];
    for (int k = 0; k < 16; ++k) { l0 += g2w[k] * h1[t][k]; l1 += g2w[16 + k] * h1[t][k]; }
    float m = fmaxf(l0, l1);
    float e0 = __expf(l0 - m), e1 = __expf(l1 - m);
    float inv = 1.f / (e0 + e1);
    cwaw[t * 2 + 0] = e0 * inv;  // conv weight
    cwaw[t * 2 + 1] = e1 * inv;  // attn weight
  }
}

// ---------------- qkv projection as MFMA GEMM: [192x64] x [64x128px] ----------------
__global__ __launch_bounds__(256) void k_qkv(const float* __restrict__ x,
                                             const float* __restrict__ wqkv,
                                             u16* __restrict__ qkv) {
  __shared__ u16 Ws[192 * 72];  // A: [row][ch], stride 72 shorts
  __shared__ u16 Xs[128 * 72];  // B^T: [px][ch]
  int t = threadIdx.x;
  int b = blockIdx.x >> 9;
  int p0 = (blockIdx.x & 511) << 7;

  // stage wqkv (192x64 fp32 -> bf16)
  {
    int row = t >> 2, c0 = (t & 3) << 4;
#pragma unroll
    for (int i = 0; i < 3; ++i) {
      int r = i * 64 + row;
      const float* src = wqkv + r * 64 + c0;
      unsigned pk[8];
#pragma unroll
      for (int j = 0; j < 8; ++j)
        pk[j] = (unsigned)f2bf(src[2 * j]) | ((unsigned)f2bf(src[2 * j + 1]) << 16);
      uint4* dst = (uint4*)&Ws[r * 72 + c0];
      dst[0] = make_uint4(pk[0], pk[1], pk[2], pk[3]);
      dst[1] = make_uint4(pk[4], pk[5], pk[6], pk[7]);
    }
  }
  // stage x tile: 64ch x 128px, transposed -> Xs[px][ch]
  {
    int p = t & 127, ch = t >> 7;
    const float* xb = x + ((size_t)(b * 64) << 16) + p0 + p;
#pragma unroll
    for (int i = 0; i < 32; ++i) {
      int c = 2 * i + ch;
      Xs[p * 72 + c] = f2bf(xb[(size_t)c << 16]);
    }
  }
  __syncthreads();

  int w = t >> 6, l = t & 63, q = l >> 4, cl = l & 15;
  bf16x8 af[3][2];
#pragma unroll
  for (int g = 0; g < 3; ++g)
#pragma unroll
    for (int k = 0; k < 2; ++k)
      af[g][k] = *(const bf16x8*)&Ws[(w * 48 + g * 16 + cl) * 72 + k * 32 + q * 8];

  f32x4 acc[3][8];
  f32x4 zero = {0.f, 0.f, 0.f, 0.f};
#pragma unroll
  for (int g = 0; g < 3; ++g)
#pragma unroll
    for (int j = 0; j < 8; ++j) acc[g][j] = zero;

  for (int j = 0; j < 8; ++j) {
    bf16x8 b0 = *(const bf16x8*)&Xs[(j * 16 + cl) * 72 + q * 8];
    bf16x8 b1 = *(const bf16x8*)&Xs[(j * 16 + cl) * 72 + 32 + q * 8];
#pragma unroll
    for (int g = 0; g < 3; ++g) {
      acc[g][j] = __builtin_amdgcn_mfma_f32_16x16x32_bf16(af[g][0], b0, acc[g][j], 0, 0, 0);
      acc[g][j] = __builtin_amdgcn_mfma_f32_16x16x32_bf16(af[g][1], b1, acc[g][j], 0, 0, 0);
    }
  }
  u16* outb = qkv + ((size_t)(b * 192) << 16) + p0;
  for (int g = 0; g < 3; ++g) {
    int rowb = w * 48 + g * 16 + q * 4;
#pragma unroll
    for (int r = 0; r < 4; ++r) {
      u16* orow = outb + ((size_t)(rowb + r) << 16);
#pragma unroll
      for (int j = 0; j < 8; ++j) orow[j * 16 + cl] = f2bf(acc[g][j][r]);
    }
  }
}

// ---------------- 1/||plane|| for q,k channels (from bf16 qkv) ----------------
__global__ void k_rnorm(const u16* __restrict__ qkv, float* __restrict__ rnorm) {
  int b = blockIdx.x >> 7, ch = blockIdx.x & 127;
  const uint2* p2 = (const uint2*)(qkv + ((size_t)(b * 192 + ch) << 16));
  int t = threadIdx.x;
  float s = 0.f;
  for (int i = 0; i < 64; ++i) {
    uint2 v = p2[t + 256 * i];
    float a = bf2f(v.x & 0xffff), bq = bf2f(v.x >> 16);
    float c = bf2f(v.y & 0xffff), d = bf2f(v.y >> 16);
    s += a * a + bq * bq + c * c + d * d;
  }
  for (int off = 32; off; off >>= 1) s += __shfl_down(s, off);
  __shared__ float lds[4];
  if ((t & 63) == 0) lds[t >> 6] = s;
  __syncthreads();
  if (t == 0) {
    float tot = lds[0] + lds[1] + lds[2] + lds[3];
    rnorm[blockIdx.x] = 1.f / fmaxf(sqrtf(tot), 1e-12f);
  }
}

// ---------------- transpose Q,K planes (512 planes) into qkvT (= d_out) ----------------
__global__ __launch_bounds__(256) void k_tr(const u16* __restrict__ qkv,
                                            u16* __restrict__ qkvT) {
  int blk = blockIdx.x;
  int tile = blk & 15;
  int pl = blk >> 4;  // b*128 + ch (ch < 128)
  int b = pl >> 7, ch = pl & 127;
  int h0 = (tile >> 2) << 6, w0 = (tile & 3) << 6;
  const u16* ip = qkv + ((size_t)(b * 192 + ch) << 16);
  u16* op = qkvT + ((size_t)pl << 16);
  __shared__ unsigned lds32[64][33];
  int t = threadIdx.x;

  int r = t >> 2, qd = t & 3;
  uint4 v0 = *(const uint4*)&ip[(size_t)(h0 + r) * 256 + w0 + qd * 16];
  uint4 v1 = *(const uint4*)&ip[(size_t)(h0 + r) * 256 + w0 + qd * 16 + 8];
  unsigned vv[8] = {v0.x, v0.y, v0.z, v0.w, v1.x, v1.y, v1.z, v1.w};
#pragma unroll
  for (int k = 0; k < 8; ++k) lds32[r][qd * 8 + k] = vv[k];
  __syncthreads();

  int wl = t >> 2, hq = t & 3;
  unsigned pkout[8];
#pragma unroll
  for (int m = 0; m < 8; ++m) {
    unsigned a = lds32[hq * 16 + 2 * m][wl >> 1];
    unsigned b2 = lds32[hq * 16 + 2 * m + 1][wl >> 1];
    pkout[m] = (wl & 1) ? ((a >> 16) | (b2 & 0xffff0000u))
                        : ((a & 0xffffu) | (b2 << 16));
  }
  *(uint4*)&op[(size_t)(w0 + wl) * 256 + h0 + hq * 16] =
      make_uint4(pkout[0], pkout[1], pkout[2], pkout[3]);
  *(uint4*)&op[(size_t)(w0 + wl) * 256 + h0 + hq * 16 + 8] =
      make_uint4(pkout[4], pkout[5], pkout[6], pkout[7]);
}

// ---------------- depthwise 3x3+5x5 conv, writes cw*conv to d_out (fp32) ----------------
__global__ void k_conv(const float* __restrict__ x, const float* __restrict__ w3,
                       const float* __restrict__ b3, const float* __restrict__ w5,
                       const float* __restrict__ b5, const float* __restrict__ cwaw,
                       float* __restrict__ outmix) {
  int rt = blockIdx.x & 31, bc = blockIdx.x >> 5, c = bc & 63, b = bc >> 6;
  int r0 = rt * 8;
  const float* xp = x + ((size_t)bc << 16);
  __shared__ float xs[12][256];
  int y = threadIdx.x;
  for (int rr = 0; rr < 12; ++rr) {
    int gr = r0 - 2 + rr;
    xs[rr][y] = (gr >= 0 && gr < 256) ? xp[(size_t)gr * 256 + y] : 0.f;
  }
  __syncthreads();
  float W3[9], W5[25];
#pragma unroll
  for (int i = 0; i < 9; ++i) W3[i] = w3[c * 9 + i];
#pragma unroll
  for (int i = 0; i < 25; ++i) W5[i] = w5[c * 25 + i];
  float bias = b3[c] + b5[c];
  float cw = cwaw[b * 2];
  float* op = outmix + ((size_t)bc << 16);
  for (int k = 0; k < 8; ++k) {
    float a = bias;
#pragma unroll
    for (int di = 0; di < 3; ++di)
#pragma unroll
      for (int dj = 0; dj < 3; ++dj) {
        int yy = y + dj - 1;
        float xv = (yy >= 0 && yy < 256) ? xs[k + 1 + di][yy] : 0.f;
        a += W3[di * 3 + dj] * xv;
      }
#pragma unroll
    for (int di = 0; di < 5; ++di)
#pragma unroll
      for (int dj = 0; dj < 5; ++dj) {
        int yy = y + dj - 2;
        float xv = (yy >= 0 && yy < 256) ? xs[k + di][yy] : 0.f;
        a += W5[di * 5 + dj] * xv;
      }
    op[(size_t)(r0 + k) * 256 + y] = cw * a;
  }
}

// ---------------- axial attention, MFMA bf16, 32-row tiles ----------------
// dir0: Q,K native rows from qkv; V^T staged full-window in LDS (R6 scheme).
// dir1: Q^T,K^T rows from qkvT (=d_out); V native rows.
__global__ __launch_bounds__(256, 4) void k_attn(
    const u16* __restrict__ qkv, const u16* __restrict__ qkvT,
    const float* __restrict__ rnorm, const float* __restrict__ scale,
    u16* __restrict__ oh, u16* __restrict__ ov) {
  __shared__ __align__(16) unsigned char smem[37888];
  u16* Pls = (u16*)smem;                       // [32][264] bf16 (16896 B)
  float* red = (float*)(smem + 16896);         // [4][32] f32 (512 B)
  unsigned* Vt32 = (unsigned*)(smem + 17408);  // [256][20] u32 (20480 B, dir0 PV)
  float* Osf = (float*)smem;                   // [32][260] f32 (dir1 store; Pls dead)

  int t = threadIdx.x;
  int w = t >> 6, l = t & 63, q = l >> 4, cl = l & 15;
  // XCD-aware bijective swizzle: a channel's 16 blocks (8 rt x 2 dir) are
  // consecutive in idx -> same 512-chunk -> same XCD -> planes stay in L2.
  int idx = (blockIdx.x & 7) * 512 + (blockIdx.x >> 3);
  int rt = idx & 7, dir = (idx >> 3) & 1, c = (idx >> 4) & 63, b = idx >> 10;
  int r0 = rt << 5;

  const size_t P = 65536;
  const u16* Qp = dir ? qkvT + (size_t)(b * 128 + c) * P : qkv + (size_t)(b * 192 + c) * P;
  const u16* Kp = dir ? qkvT + (size_t)(b * 128 + 64 + c) * P : qkv + (size_t)(b * 192 + 64 + c) * P;
  const u16* Vp = qkv + (size_t)(b * 192 + 128 + c) * P;  // always native V

  float sc = rnorm[b * 128 + c] * rnorm[b * 128 + 64 + c] * scale[c >> 3];

  f32x4 Sa[2][4];
  f32x4 zero = {0.f, 0.f, 0.f, 0.f};
#pragma unroll
  for (int i = 0; i < 2; ++i)
#pragma unroll
    for (int j = 0; j < 4; ++j) Sa[i][j] = zero;

  // ---- S phase: 8 k-windows of 32, all coalesced bf16x8 row loads ----
  for (int yw = 0; yw < 8; ++yw) {
    int y0 = yw << 5;
    bf16x8 af[2], bfr[4];
#pragma unroll
    for (int i = 0; i < 2; ++i)
      af[i] = *(const bf16x8*)&Qp[(size_t)(r0 + i * 16 + cl) * 256 + y0 + q * 8];
#pragma unroll
    for (int j = 0; j < 4; ++j)
      bfr[j] = *(const bf16x8*)&Kp[(size_t)(w * 64 + j * 16 + cl) * 256 + y0 + q * 8];
#pragma unroll
    for (int i = 0; i < 2; ++i)
#pragma unroll
      for (int j = 0; j < 4; ++j)
        Sa[i][j] = __builtin_amdgcn_mfma_f32_16x16x32_bf16(af[i], bfr[j], Sa[i][j], 0, 0, 0);
  }

  // ---- softmax over cols, NO max pass: |S*sc| <= scale = 1 ----
  float sm[2][4];
#pragma unroll
  for (int i = 0; i < 2; ++i)
#pragma unroll
    for (int r = 0; r < 4; ++r) {
      float s0 = 0.f;
#pragma unroll
      for (int j = 0; j < 4; ++j) {
        float e = __expf(Sa[i][j][r] * sc);
        Sa[i][j][r] = e;
        s0 += e;
      }
#pragma unroll
      for (int off = 1; off < 16; off <<= 1) s0 += __shfl_xor(s0, off);
      sm[i][r] = s0;
    }
  if (cl == 0) {
#pragma unroll
    for (int i = 0; i < 2; ++i)
#pragma unroll
      for (int r = 0; r < 4; ++r) red[w * 32 + i * 16 + q * 4 + r] = sm[i][r];
  }
  __syncthreads();
#pragma unroll
  for (int i = 0; i < 2; ++i)
#pragma unroll
    for (int r = 0; r < 4; ++r) {
      int rho = i * 16 + q * 4 + r;
      sm[i][r] = 1.f / (red[rho] + red[32 + rho] + red[64 + rho] + red[96 + rho]);
    }
  // P -> Pls [32][264]
#pragma unroll
  for (int i = 0; i < 2; ++i)
#pragma unroll
    for (int r = 0; r < 4; ++r) {
      int rho = i * 16 + q * 4 + r;
#pragma unroll
      for (int j = 0; j < 4; ++j)
        Pls[rho * 264 + w * 64 + j * 16 + cl] = f2bf(Sa[i][j][r] * sm[i][r]);
    }
  __syncthreads();

  // ---- O = P V over 8 z-windows ----
  f32x4 Oa[2][4];
#pragma unroll
  for (int i = 0; i < 2; ++i)
#pragma unroll
    for (int j = 0; j < 4; ++j) Oa[i][j] = zero;

  if (dir == 0) {
    // stage V^T per window (R6 scheme): thread (z2=t>>4, colc=t&15) loads rows
    // z0+2*z2, +1 (coalesced), packs pairs into u32, writes swizzled Vt32.
    int z2 = t >> 4, colc = t & 15;
    int zlo = z2 & 3;
    int wkey = (((z2 >> 2) ^ (colc & 3)) << 2) + zlo;
    for (int zw = 0; zw < 8; ++zw) {
      int z0 = zw << 5;
      const u16* rp = Vp + (size_t)(z0 + 2 * z2) * 256 + colc * 16;
      uint4 a0 = *(const uint4*)rp;
      uint4 a1 = *(const uint4*)(rp + 8);
      uint4 c0 = *(const uint4*)(rp + 256);
      uint4 c1 = *(const uint4*)(rp + 264);
      unsigned A[8] = {a0.x, a0.y, a0.z, a0.w, a1.x, a1.y, a1.z, a1.w};
      unsigned Bv[8] = {c0.x, c0.y, c0.z, c0.w, c1.x, c1.y, c1.z, c1.w};
      __syncthreads();  // previous window's Vt reads complete
#pragma unroll
      for (int m = 0; m < 16; ++m) {
        unsigned lo = (m & 1) ? (A[m >> 1] >> 16) : (A[m >> 1] & 0xffffu);
        unsigned hi = (m & 1) ? (Bv[m >> 1] & 0xffff0000u) : (Bv[m >> 1] << 16);
        Vt32[(colc * 16 + m) * 20 + wkey] = lo | hi;
      }
      __syncthreads();
      bf16x8 af[2], bfr[4];
#pragma unroll
      for (int i = 0; i < 2; ++i)
        af[i] = *(const bf16x8*)&Pls[(i * 16 + cl) * 264 + z0 + q * 8];
#pragma unroll
      for (int j = 0; j < 4; ++j) {
        int col = w * 64 + j * 16 + cl;
        bfr[j] = *(const bf16x8*)&Vt32[col * 20 + ((q ^ j) << 2)];
      }
#pragma unroll
      for (int i = 0; i < 2; ++i)
#pragma unroll
        for (int j = 0; j < 4; ++j)
          Oa[i][j] = __builtin_amdgcn_mfma_f32_16x16x32_bf16(af[i], bfr[j], Oa[i][j], 0, 0, 0);
    }
    u16* op = oh + (size_t)(b * 64 + c) * P;
#pragma unroll
    for (int i = 0; i < 2; ++i)
#pragma unroll
      for (int j = 0; j < 4; ++j)
#pragma unroll
        for (int r = 0; r < 4; ++r)
          op[(size_t)(r0 + i * 16 + q * 4 + r) * 256 + w * 64 + j * 16 + cl] = f2bf(Oa[i][j][r]);
  } else {
    for (int zw = 0; zw < 8; ++zw) {
      int z0 = zw << 5;
      bf16x8 af[2], bfr[4];
#pragma unroll
      for (int i = 0; i < 2; ++i)
        af[i] = *(const bf16x8*)&Pls[(i * 16 + cl) * 264 + z0 + q * 8];
#pragma unroll
      for (int j = 0; j < 4; ++j)
        bfr[j] = *(const bf16x8*)&Vp[(size_t)(w * 64 + j * 16 + cl) * 256 + z0 + q * 8];
#pragma unroll
      for (int i = 0; i < 2; ++i)
#pragma unroll
        for (int j = 0; j < 4; ++j)
          Oa[i][j] = __builtin_amdgcn_mfma_f32_16x16x32_bf16(af[i], bfr[j], Oa[i][j], 0, 0, 0);
    }
    // transposed store via LDS (Pls dead; barrier-protected)
    u16* op = ov + (size_t)(b * 64 + c) * P;
    __syncthreads();
#pragma unroll
    for (int i = 0; i < 2; ++i)
#pragma unroll
      for (int j = 0; j < 4; ++j)
#pragma unroll
        for (int r = 0; r < 4; ++r)
          Osf[(i * 16 + q * 4 + r) * 260 + w * 64 + j * 16 + cl] = Oa[i][j][r];
    __syncthreads();
    int rr = t & 31, xb = t >> 5;
    for (int xx = 0; xx < 32; ++xx) {
      int xcol = xx * 8 + xb;
      op[(size_t)xcol * 256 + r0 + rr] = f2bf(Osf[rr * 260 + xcol]);
    }
  }
}

// ---------------- mix + 64x64 projection as MFMA GEMM, in place on d_out ----------------
__global__ __launch_bounds__(256) void k_final(
    float* __restrict__ dout, const u16* __restrict__ oh, const u16* __restrict__ ov,
    const float* __restrict__ wp, const float* __restrict__ bp,
    const float* __restrict__ cwaw) {
  __shared__ u16 Ms[256 * 72];  // B^T: [px][ch]
  __shared__ u16 Ws[64 * 72];   // A: [row][ch]
  int t = threadIdx.x;
  int b = blockIdx.x >> 8;
  int p0 = (blockIdx.x & 255) << 8;
  float aw = cwaw[b * 2 + 1];

  {
    int row = t >> 2, c0 = (t & 3) << 4;
    const float* src = wp + row * 64 + c0;
    unsigned pk[8];
#pragma unroll
    for (int j = 0; j < 8; ++j)
      pk[j] = (unsigned)f2bf(src[2 * j]) | ((unsigned)f2bf(src[2 * j + 1]) << 16);
    uint4* dst = (uint4*)&Ws[row * 72 + c0];
    dst[0] = make_uint4(pk[0], pk[1], pk[2], pk[3]);
    dst[1] = make_uint4(pk[4], pk[5], pk[6], pk[7]);
  }
  {
    size_t base = ((size_t)(b * 64) << 16) + p0 + t;
    for (int c = 0; c < 64; ++c) {
      size_t off = base + ((size_t)c << 16);
      float m = dout[off] + aw * (bf2f(oh[off]) + bf2f(ov[off]));
      Ms[t * 72 + c] = f2bf(m);
    }
  }
  __syncthreads();

  int w = t >> 6, l = t & 63, q = l >> 4, cl = l & 15;
  bf16x8 af0 = *(const bf16x8*)&Ws[(w * 16 + cl) * 72 + q * 8];
  bf16x8 af1 = *(const bf16x8*)&Ws[(w * 16 + cl) * 72 + 32 + q * 8];

  f32x4 acc[16];
  f32x4 zero = {0.f, 0.f, 0.f, 0.f};
#pragma unroll
  for (int j = 0; j < 16; ++j) acc[j] = zero;

  for (int j = 0; j < 16; ++j) {
    bf16x8 b0 = *(const bf16x8*)&Ms[(j * 16 + cl) * 72 + q * 8];
    bf16x8 b1 = *(const bf16x8*)&Ms[(j * 16 + cl) * 72 + 32 + q * 8];
    acc[j] = __builtin_amdgcn_mfma_f32_16x16x32_bf16(af0, b0, acc[j], 0, 0, 0);
    acc[j] = __builtin_amdgcn_mfma_f32_16x16x32_bf16(af1, b1, acc[j], 0, 0, 0);
  }

  float bpv[4];
#pragma unroll
  for (int r = 0; r < 4; ++r) bpv[r] = bp[w * 16 + q * 4 + r];
  float* outb = dout + ((size_t)(b * 64) << 16) + p0;
#pragma unroll
  for (int r = 0; r < 4; ++r) {
    float* orow = outb + ((size_t)(w * 16 + q * 4 + r) << 16);
#pragma unroll
    for (int j = 0; j < 16; ++j) orow[j * 16 + cl] = acc[j][r] + bpv[r];
  }
}

extern "C" void kernel_launch(void* const* d_in, const int* in_sizes, int n_in,
                              void* d_out, int out_size, void* d_ws, size_t ws_size,
                              hipStream_t stream) {
  const float* x = (const float*)d_in[0];
  const float* w3 = (const float*)d_in[1];
  const float* b3 = (const float*)d_in[2];
  const float* w5 = (const float*)d_in[3];
  const float* b5 = (const float*)d_in[4];
  const float* wqkv = (const float*)d_in[5];
  const float* scale = (const float*)d_in[6];
  const float* g1w = (const float*)d_in[7];
  const float* g1b = (const float*)d_in[8];
  const float* g2w = (const float*)d_in[9];
  const float* g2b = (const float*)d_in[10];
  const float* wp = (const float*)d_in[11];
  const float* bp = (const float*)d_in[12];
  float* out = (float*)d_out;

  char* ws = (char*)d_ws;
  u16* qkv = (u16*)(ws);
  u16* ohb = (u16*)(ws + 100663296ull);
  u16* ovb = (u16*)(ws + 134217728ull);
  float* fs = (float*)(ws + 167772160ull);
  float* gxsum = fs;        // 256
  float* cwaw = fs + 256;   // 8
  float* rnorm = fs + 264;  // 512
  u16* qkvT = (u16*)d_out;  // 64 MiB, dead until k_conv overwrites it

  k_gx<<<256, 256, 0, stream>>>(x, gxsum);
  k_gate<<<1, 64, 0, stream>>>(gxsum, g1w, g1b, g2w, g2b, cwaw);
  k_qkv<<<2048, 256, 0, stream>>>(x, wqkv, qkv);
  k_rnorm<<<512, 256, 0, stream>>>(qkv, rnorm);
  k_tr<<<8192, 256, 0, stream>>>(qkv, qkvT);
  k_attn<<<4096, 256, 0, stream>>>(qkv, qkvT, rnorm, scale, ohb, ovb);
  k_conv<<<8192, 256, 0, stream>>>(x, w3, b3, w5, b5, cwaw, out);
  k_final<<<1024, 256, 0, stream>>>(out, ohb, ovb, wp, bp, cwaw);
}

// Round 6
// 355.001 us; speedup vs baseline: 1.1832x; 1.1775x over previous
//
#include <hip/hip_runtime.h>
#include <stdint.h>

// CAFormer fused block, MI355X gfx950.
// R9: R8 regressed (32-row tiles doubled staging+barrier work; occupancy was
// not the binding limit). Revert to R6's 64-row k_attn, and ELIMINATE k_tr
// (measured ~62us) by staging dir1's Q^T/K^T in-kernel per y-window using the
// exact V^T-staging scheme proven in R6's dir0 PV. Both dirs now read only
// native qkv planes; qkvT / d_out aliasing gone. Keep no-max softmax
// (|S*sc| <= scale, plane-L2norm Cauchy-Schwarz; validated R7/R8).
// ws layout (160 MiB + 3088 B, proven):
//   qkv bf16 [4][192][65536] @ 0          (100663296 B)
//   oh  bf16 [4][64][65536]  @ 100663296  (33554432 B)
//   ov  bf16                 @ 134217728  (33554432 B)
//   f32 scratch @ 167772160: gxsum[256] cwaw[8] rnorm[512]

typedef unsigned short u16;
typedef __attribute__((ext_vector_type(8))) short bf16x8;
typedef __attribute__((ext_vector_type(4))) float f32x4;

#define DEV static __device__ __forceinline__

DEV u16 f2bf(float f) {
  unsigned u = __float_as_uint(f);
  return (u16)((u + 0x7fffu + ((u >> 16) & 1u)) >> 16);
}
DEV float bf2f(u16 h) { return __uint_as_float(((unsigned)h) << 16); }

// ---------------- gating: per-(b,c) spatial sum of x ----------------
__global__ void k_gx(const float* __restrict__ x, float* __restrict__ gxsum) {
  int bc = blockIdx.x, t = threadIdx.x;
  const float4* p = (const float4*)(x + ((size_t)bc << 16));
  float s = 0.f;
  for (int i = 0; i < 64; ++i) { float4 v = p[t + 256 * i]; s += v.x + v.y + v.z + v.w; }
  for (int off = 32; off; off >>= 1) s += __shfl_down(s, off);
  __shared__ float lds[4];
  if ((t & 63) == 0) lds[t >> 6] = s;
  __syncthreads();
  if (t == 0) gxsum[bc] = lds[0] + lds[1] + lds[2] + lds[3];
}

// ---------------- gating MLP -> cw/aw per batch ----------------
__global__ void k_gate(const float* __restrict__ gxsum, const float* __restrict__ g1w,
                       const float* __restrict__ g1b, const float* __restrict__ g2w,
                       const float* __restrict__ g2b, float* __restrict__ cwaw) {
  __shared__ float h1[4][16];
  int t = threadIdx.x;
  int b = t >> 4, j = t & 15;
  float a = g1b[j];
  for (int c = 0; c < 64; ++c) a += g1w[j * 64 + c] * gxsum[b * 64 + c] * (1.f / 65536.f);
  h1[b][j] = fmaxf(a, 0.f);
  __syncthreads();
  if (t < 4) {
    float l0 = g2b[0], l1 = g2b[1];
    for (int k = 0; k < 16; ++k) { l0 += g2w[k] * h1[t][k]; l1 += g2w[16 + k] * h1[t][k]; }
    float m = fmaxf(l0, l1);
    float e0 = __expf(l0 - m), e1 = __expf(l1 - m);
    float inv = 1.f / (e0 + e1);
    cwaw[t * 2 + 0] = e0 * inv;  // conv weight
    cwaw[t * 2 + 1] = e1 * inv;  // attn weight
  }
}

// ---------------- qkv projection as MFMA GEMM: [192x64] x [64x128px] ----------------
__global__ __launch_bounds__(256) void k_qkv(const float* __restrict__ x,
                                             const float* __restrict__ wqkv,
                                             u16* __restrict__ qkv) {
  __shared__ u16 Ws[192 * 72];  // A: [row][ch], stride 72 shorts
  __shared__ u16 Xs[128 * 72];  // B^T: [px][ch]
  int t = threadIdx.x;
  int b = blockIdx.x >> 9;
  int p0 = (blockIdx.x & 511) << 7;

  // stage wqkv (192x64 fp32 -> bf16)
  {
    int row = t >> 2, c0 = (t & 3) << 4;
#pragma unroll
    for (int i = 0; i < 3; ++i) {
      int r = i * 64 + row;
      const float* src = wqkv + r * 64 + c0;
      unsigned pk[8];
#pragma unroll
      for (int j = 0; j < 8; ++j)
        pk[j] = (unsigned)f2bf(src[2 * j]) | ((unsigned)f2bf(src[2 * j + 1]) << 16);
      uint4* dst = (uint4*)&Ws[r * 72 + c0];
      dst[0] = make_uint4(pk[0], pk[1], pk[2], pk[3]);
      dst[1] = make_uint4(pk[4], pk[5], pk[6], pk[7]);
    }
  }
  // stage x tile: 64ch x 128px, transposed -> Xs[px][ch]
  {
    int p = t & 127, ch = t >> 7;
    const float* xb = x + ((size_t)(b * 64) << 16) + p0 + p;
#pragma unroll
    for (int i = 0; i < 32; ++i) {
      int c = 2 * i + ch;
      Xs[p * 72 + c] = f2bf(xb[(size_t)c << 16]);
    }
  }
  __syncthreads();

  int w = t >> 6, l = t & 63, q = l >> 4, cl = l & 15;
  bf16x8 af[3][2];
#pragma unroll
  for (int g = 0; g < 3; ++g)
#pragma unroll
    for (int k = 0; k < 2; ++k)
      af[g][k] = *(const bf16x8*)&Ws[(w * 48 + g * 16 + cl) * 72 + k * 32 + q * 8];

  f32x4 acc[3][8];
  f32x4 zero = {0.f, 0.f, 0.f, 0.f};
#pragma unroll
  for (int g = 0; g < 3; ++g)
#pragma unroll
    for (int j = 0; j < 8; ++j) acc[g][j] = zero;

  for (int j = 0; j < 8; ++j) {
    bf16x8 b0 = *(const bf16x8*)&Xs[(j * 16 + cl) * 72 + q * 8];
    bf16x8 b1 = *(const bf16x8*)&Xs[(j * 16 + cl) * 72 + 32 + q * 8];
#pragma unroll
    for (int g = 0; g < 3; ++g) {
      acc[g][j] = __builtin_amdgcn_mfma_f32_16x16x32_bf16(af[g][0], b0, acc[g][j], 0, 0, 0);
      acc[g][j] = __builtin_amdgcn_mfma_f32_16x16x32_bf16(af[g][1], b1, acc[g][j], 0, 0, 0);
    }
  }
  u16* outb = qkv + ((size_t)(b * 192) << 16) + p0;
  for (int g = 0; g < 3; ++g) {
    int rowb = w * 48 + g * 16 + q * 4;
#pragma unroll
    for (int r = 0; r < 4; ++r) {
      u16* orow = outb + ((size_t)(rowb + r) << 16);
#pragma unroll
      for (int j = 0; j < 8; ++j) orow[j * 16 + cl] = f2bf(acc[g][j][r]);
    }
  }
}

// ---------------- 1/||plane|| for q,k channels (from bf16 qkv) ----------------
__global__ void k_rnorm(const u16* __restrict__ qkv, float* __restrict__ rnorm) {
  int b = blockIdx.x >> 7, ch = blockIdx.x & 127;
  const uint2* p2 = (const uint2*)(qkv + ((size_t)(b * 192 + ch) << 16));
  int t = threadIdx.x;
  float s = 0.f;
  for (int i = 0; i < 64; ++i) {
    uint2 v = p2[t + 256 * i];
    float a = bf2f(v.x & 0xffff), bq = bf2f(v.x >> 16);
    float c = bf2f(v.y & 0xffff), d = bf2f(v.y >> 16);
    s += a * a + bq * bq + c * c + d * d;
  }
  for (int off = 32; off; off >>= 1) s += __shfl_down(s, off);
  __shared__ float lds[4];
  if ((t & 63) == 0) lds[t >> 6] = s;
  __syncthreads();
  if (t == 0) {
    float tot = lds[0] + lds[1] + lds[2] + lds[3];
    rnorm[blockIdx.x] = 1.f / fmaxf(sqrtf(tot), 1e-12f);
  }
}

// ---------------- depthwise 3x3+5x5 conv, writes cw*conv to d_out (fp32) ----------------
__global__ void k_conv(const float* __restrict__ x, const float* __restrict__ w3,
                       const float* __restrict__ b3, const float* __restrict__ w5,
                       const float* __restrict__ b5, const float* __restrict__ cwaw,
                       float* __restrict__ outmix) {
  int rt = blockIdx.x & 31, bc = blockIdx.x >> 5, c = bc & 63, b = bc >> 6;
  int r0 = rt * 8;
  const float* xp = x + ((size_t)bc << 16);
  __shared__ float xs[12][256];
  int y = threadIdx.x;
  for (int rr = 0; rr < 12; ++rr) {
    int gr = r0 - 2 + rr;
    xs[rr][y] = (gr >= 0 && gr < 256) ? xp[(size_t)gr * 256 + y] : 0.f;
  }
  __syncthreads();
  float W3[9], W5[25];
#pragma unroll
  for (int i = 0; i < 9; ++i) W3[i] = w3[c * 9 + i];
#pragma unroll
  for (int i = 0; i < 25; ++i) W5[i] = w5[c * 25 + i];
  float bias = b3[c] + b5[c];
  float cw = cwaw[b * 2];
  float* op = outmix + ((size_t)bc << 16);
  for (int k = 0; k < 8; ++k) {
    float a = bias;
#pragma unroll
    for (int di = 0; di < 3; ++di)
#pragma unroll
      for (int dj = 0; dj < 3; ++dj) {
        int yy = y + dj - 1;
        float xv = (yy >= 0 && yy < 256) ? xs[k + 1 + di][yy] : 0.f;
        a += W3[di * 3 + dj] * xv;
      }
#pragma unroll
    for (int di = 0; di < 5; ++di)
#pragma unroll
      for (int dj = 0; dj < 5; ++dj) {
        int yy = y + dj - 2;
        float xv = (yy >= 0 && yy < 256) ? xs[k + di][yy] : 0.f;
        a += W5[di * 5 + dj] * xv;
      }
    op[(size_t)(r0 + k) * 256 + y] = cw * a;
  }
}

// ---------------- axial attention, MFMA bf16, 64-row tiles, no qkvT ----------------
// dir0: S direct (native Q,K rows); PV stages V^T per z-window in LDS (R6 scheme).
// dir1: S stages Q^T (64-wide) + K^T (256-wide) per y-window (same scheme);
//       PV direct (native V rows).
__global__ __launch_bounds__(256) void k_attn(
    const u16* __restrict__ qkv, const float* __restrict__ rnorm,
    const float* __restrict__ scale, u16* __restrict__ oh, u16* __restrict__ ov) {
  __shared__ __align__(16) unsigned char smem[54272];
  u16* Pls = (u16*)smem;                       // [64][264] bf16 (33792 B)
  unsigned* Qt32 = (unsigned*)smem;            // [64][20] u32 (5120 B; dir1 S, Pls dead)
  float* red = (float*)(smem + 33792);         // [4][64] f32
  unsigned* Tt32 = (unsigned*)(smem + 33792);  // [256][20] u32 (20480 B; Kt dir1-S / Vt dir0-PV)
  float* Osf = (float*)smem;                   // [32][260] f32 (dir1 store; Pls dead)

  int t = threadIdx.x;
  int w = t >> 6, l = t & 63, q = l >> 4, cl = l & 15;
  // XCD-aware bijective swizzle: one channel's 8 blocks (4 rt x 2 dir) are
  // consecutive in idx -> same XCD -> planes shared in that XCD's L2.
  int idx = (blockIdx.x & 7) * 256 + (blockIdx.x >> 3);
  int rt = idx & 3, dir = (idx >> 2) & 1, c = (idx >> 3) & 63, b = idx >> 9;
  int r0 = rt << 6;

  const size_t P = 65536;
  const u16* Qp = qkv + (size_t)(b * 192 + c) * P;
  const u16* Kp = qkv + (size_t)(b * 192 + 64 + c) * P;
  const u16* Vp = qkv + (size_t)(b * 192 + 128 + c) * P;

  float sc = rnorm[b * 128 + c] * rnorm[b * 128 + 64 + c] * scale[c >> 3];

  f32x4 Sa[4][4];
  f32x4 zero = {0.f, 0.f, 0.f, 0.f};
#pragma unroll
  for (int i = 0; i < 4; ++i)
#pragma unroll
    for (int j = 0; j < 4; ++j) Sa[i][j] = zero;

  // ---- S phase: 8 k-windows of 32 ----
  if (dir == 0) {
    for (int yw = 0; yw < 8; ++yw) {
      int y0 = yw << 5;
      bf16x8 af[4], bfr[4];
#pragma unroll
      for (int i = 0; i < 4; ++i)
        af[i] = *(const bf16x8*)&Qp[(size_t)(r0 + i * 16 + cl) * 256 + y0 + q * 8];
#pragma unroll
      for (int j = 0; j < 4; ++j)
        bfr[j] = *(const bf16x8*)&Kp[(size_t)(w * 64 + j * 16 + cl) * 256 + y0 + q * 8];
#pragma unroll
      for (int i = 0; i < 4; ++i)
#pragma unroll
        for (int j = 0; j < 4; ++j)
          Sa[i][j] = __builtin_amdgcn_mfma_f32_16x16x32_bf16(af[i], bfr[j], Sa[i][j], 0, 0, 0);
    }
  } else {
    // stage K^T (full 256 cols) + Q^T (64 cols at r0) per window.
    int y2 = t >> 4, colc = t & 15;
    int kkey = (((y2 >> 2) ^ (colc & 3)) << 2) + (y2 & 3);
    int qkey = (((y2 >> 2) ^ ((colc >> 2) & 3)) << 2) + (y2 & 3);
    for (int yw = 0; yw < 8; ++yw) {
      int y0 = yw << 5;
      const u16* krp = Kp + (size_t)(y0 + 2 * y2) * 256 + colc * 16;
      uint4 ka0 = *(const uint4*)krp;
      uint4 ka1 = *(const uint4*)(krp + 8);
      uint4 kb0 = *(const uint4*)(krp + 256);
      uint4 kb1 = *(const uint4*)(krp + 264);
      const u16* qrp = Qp + (size_t)(y0 + 2 * y2) * 256 + r0 + colc * 4;
      uint2 qa = *(const uint2*)qrp;
      uint2 qb = *(const uint2*)(qrp + 256);
      unsigned KA[8] = {ka0.x, ka0.y, ka0.z, ka0.w, ka1.x, ka1.y, ka1.z, ka1.w};
      unsigned KB[8] = {kb0.x, kb0.y, kb0.z, kb0.w, kb1.x, kb1.y, kb1.z, kb1.w};
      unsigned QA[2] = {qa.x, qa.y};
      unsigned QB[2] = {qb.x, qb.y};
      __syncthreads();  // previous window's LDS reads complete
#pragma unroll
      for (int m = 0; m < 16; ++m) {
        unsigned lo = (m & 1) ? (KA[m >> 1] >> 16) : (KA[m >> 1] & 0xffffu);
        unsigned hi = (m & 1) ? (KB[m >> 1] & 0xffff0000u) : (KB[m >> 1] << 16);
        Tt32[(colc * 16 + m) * 20 + kkey] = lo | hi;
      }
#pragma unroll
      for (int m = 0; m < 4; ++m) {
        unsigned lo = (m & 1) ? (QA[m >> 1] >> 16) : (QA[m >> 1] & 0xffffu);
        unsigned hi = (m & 1) ? (QB[m >> 1] & 0xffff0000u) : (QB[m >> 1] << 16);
        Qt32[(colc * 4 + m) * 20 + qkey] = lo | hi;
      }
      __syncthreads();
      bf16x8 af[4], bfr[4];
#pragma unroll
      for (int i = 0; i < 4; ++i)
        af[i] = *(const bf16x8*)&Qt32[(i * 16 + cl) * 20 + ((q ^ i) << 2)];
#pragma unroll
      for (int j = 0; j < 4; ++j) {
        int col = w * 64 + j * 16 + cl;
        bfr[j] = *(const bf16x8*)&Tt32[col * 20 + ((q ^ j) << 2)];
      }
#pragma unroll
      for (int i = 0; i < 4; ++i)
#pragma unroll
        for (int j = 0; j < 4; ++j)
          Sa[i][j] = __builtin_amdgcn_mfma_f32_16x16x32_bf16(af[i], bfr[j], Sa[i][j], 0, 0, 0);
    }
    __syncthreads();  // close Qt32/Tt32 reads before red/Pls writes
  }

  // ---- softmax over cols, NO max pass: |S*sc| <= scale ----
  float sm[4][4];
#pragma unroll
  for (int i = 0; i < 4; ++i)
#pragma unroll
    for (int r = 0; r < 4; ++r) {
      float s0 = 0.f;
#pragma unroll
      for (int j = 0; j < 4; ++j) {
        float e = __expf(Sa[i][j][r] * sc);
        Sa[i][j][r] = e;
        s0 += e;
      }
#pragma unroll
      for (int off = 1; off < 16; off <<= 1) s0 += __shfl_xor(s0, off);
      sm[i][r] = s0;
    }
  if (cl == 0) {
#pragma unroll
    for (int i = 0; i < 4; ++i)
#pragma unroll
      for (int r = 0; r < 4; ++r) red[w * 64 + i * 16 + q * 4 + r] = sm[i][r];
  }
  __syncthreads();
#pragma unroll
  for (int i = 0; i < 4; ++i)
#pragma unroll
    for (int r = 0; r < 4; ++r) {
      int rho = i * 16 + q * 4 + r;
      sm[i][r] = 1.f / (red[rho] + red[64 + rho] + red[128 + rho] + red[192 + rho]);
    }
  // P -> Pls row-major [row][z]
#pragma unroll
  for (int i = 0; i < 4; ++i)
#pragma unroll
    for (int r = 0; r < 4; ++r) {
      int rho = i * 16 + q * 4 + r;
#pragma unroll
      for (int j = 0; j < 4; ++j)
        Pls[rho * 264 + w * 64 + j * 16 + cl] = f2bf(Sa[i][j][r] * sm[i][r]);
    }
  __syncthreads();

  // ---- O = P V over 8 z-windows ----
  f32x4 Oa[4][4];
#pragma unroll
  for (int i = 0; i < 4; ++i)
#pragma unroll
    for (int j = 0; j < 4; ++j) Oa[i][j] = zero;

  if (dir == 0) {
    // stage V^T per window (R6 proven scheme)
    int z2 = t >> 4, colc = t & 15;
    int zlo = z2 & 3;
    int wkey = (((z2 >> 2) ^ (colc & 3)) << 2) + zlo;
    for (int zw = 0; zw < 8; ++zw) {
      int z0 = zw << 5;
      const u16* rp = Vp + (size_t)(z0 + 2 * z2) * 256 + colc * 16;
      uint4 a0 = *(const uint4*)rp;
      uint4 a1 = *(const uint4*)(rp + 8);
      uint4 c0 = *(const uint4*)(rp + 256);
      uint4 c1 = *(const uint4*)(rp + 264);
      unsigned A[8] = {a0.x, a0.y, a0.z, a0.w, a1.x, a1.y, a1.z, a1.w};
      unsigned Bv[8] = {c0.x, c0.y, c0.z, c0.w, c1.x, c1.y, c1.z, c1.w};
      __syncthreads();  // previous window's Vt reads complete
#pragma unroll
      for (int m = 0; m < 16; ++m) {
        unsigned lo = (m & 1) ? (A[m >> 1] >> 16) : (A[m >> 1] & 0xffffu);
        unsigned hi = (m & 1) ? (Bv[m >> 1] & 0xffff0000u) : (Bv[m >> 1] << 16);
        Tt32[(colc * 16 + m) * 20 + wkey] = lo | hi;
      }
      __syncthreads();
      bf16x8 af[4], bfr[4];
#pragma unroll
      for (int i = 0; i < 4; ++i)
        af[i] = *(const bf16x8*)&Pls[(i * 16 + cl) * 264 + z0 + q * 8];
#pragma unroll
      for (int j = 0; j < 4; ++j) {
        int col = w * 64 + j * 16 + cl;
        bfr[j] = *(const bf16x8*)&Tt32[col * 20 + ((q ^ j) << 2)];
      }
#pragma unroll
      for (int i = 0; i < 4; ++i)
#pragma unroll
        for (int j = 0; j < 4; ++j)
          Oa[i][j] = __builtin_amdgcn_mfma_f32_16x16x32_bf16(af[i], bfr[j], Oa[i][j], 0, 0, 0);
    }
    u16* op = oh + (size_t)(b * 64 + c) * P;
#pragma unroll
    for (int i = 0; i < 4; ++i)
#pragma unroll
      for (int j = 0; j < 4; ++j)
#pragma unroll
        for (int r = 0; r < 4; ++r)
          op[(size_t)(r0 + i * 16 + q * 4 + r) * 256 + w * 64 + j * 16 + cl] = f2bf(Oa[i][j][r]);
  } else {
    for (int zw = 0; zw < 8; ++zw) {
      int z0 = zw << 5;
      bf16x8 af[4], bfr[4];
#pragma unroll
      for (int i = 0; i < 4; ++i)
        af[i] = *(const bf16x8*)&Pls[(i * 16 + cl) * 264 + z0 + q * 8];
#pragma unroll
      for (int j = 0; j < 4; ++j)
        bfr[j] = *(const bf16x8*)&Vp[(size_t)(w * 64 + j * 16 + cl) * 256 + z0 + q * 8];
#pragma unroll
      for (int i = 0; i < 4; ++i)
#pragma unroll
        for (int j = 0; j < 4; ++j)
          Oa[i][j] = __builtin_amdgcn_mfma_f32_16x16x32_bf16(af[i], bfr[j], Oa[i][j], 0, 0, 0);
    }
    // transposed store via LDS (Pls dead; barrier-protected)
    u16* op = ov + (size_t)(b * 64 + c) * P;
    __syncthreads();
    for (int h = 0; h < 2; ++h) {
#pragma unroll
      for (int ii = 0; ii < 2; ++ii) {
        int i = h * 2 + ii;
#pragma unroll
        for (int j = 0; j < 4; ++j)
#pragma unroll
          for (int r = 0; r < 4; ++r)
            Osf[(ii * 16 + q * 4 + r) * 260 + w * 64 + j * 16 + cl] = Oa[i][j][r];
      }
      __syncthreads();
      int rr = t & 31, xb = t >> 5;
      for (int xx = 0; xx < 32; ++xx) {
        int xcol = xx * 8 + xb;
        op[(size_t)xcol * 256 + r0 + h * 32 + rr] = f2bf(Osf[rr * 260 + xcol]);
      }
      __syncthreads();
    }
  }
}

// ---------------- mix + 64x64 projection as MFMA GEMM, in place on d_out ----------------
__global__ __launch_bounds__(256) void k_final(
    float* __restrict__ dout, const u16* __restrict__ oh, const u16* __restrict__ ov,
    const float* __restrict__ wp, const float* __restrict__ bp,
    const float* __restrict__ cwaw) {
  __shared__ u16 Ms[256 * 72];  // B^T: [px][ch]
  __shared__ u16 Ws[64 * 72];   // A: [row][ch]
  int t = threadIdx.x;
  int b = blockIdx.x >> 8;
  int p0 = (blockIdx.x & 255) << 8;
  float aw = cwaw[b * 2 + 1];

  {
    int row = t >> 2, c0 = (t & 3) << 4;
    const float* src = wp + row * 64 + c0;
    unsigned pk[8];
#pragma unroll
    for (int j = 0; j < 8; ++j)
      pk[j] = (unsigned)f2bf(src[2 * j]) | ((unsigned)f2bf(src[2 * j + 1]) << 16);
    uint4* dst = (uint4*)&Ws[row * 72 + c0];
    dst[0] = make_uint4(pk[0], pk[1], pk[2], pk[3]);
    dst[1] = make_uint4(pk[4], pk[5], pk[6], pk[7]);
  }
  {
    size_t base = ((size_t)(b * 64) << 16) + p0 + t;
    for (int c = 0; c < 64; ++c) {
      size_t off = base + ((size_t)c << 16);
      float m = dout[off] + aw * (bf2f(oh[off]) + bf2f(ov[off]));
      Ms[t * 72 + c] = f2bf(m);
    }
  }
  __syncthreads();

  int w = t >> 6, l = t & 63, q = l >> 4, cl = l & 15;
  bf16x8 af0 = *(const bf16x8*)&Ws[(w * 16 + cl) * 72 + q * 8];
  bf16x8 af1 = *(const bf16x8*)&Ws[(w * 16 + cl) * 72 + 32 + q * 8];

  f32x4 acc[16];
  f32x4 zero = {0.f, 0.f, 0.f, 0.f};
#pragma unroll
  for (int j = 0; j < 16; ++j) acc[j] = zero;

  for (int j = 0; j < 16; ++j) {
    bf16x8 b0 = *(const bf16x8*)&Ms[(j * 16 + cl) * 72 + q * 8];
    bf16x8 b1 = *(const bf16x8*)&Ms[(j * 16 + cl) * 72 + 32 + q * 8];
    acc[j] = __builtin_amdgcn_mfma_f32_16x16x32_bf16(af0, b0, acc[j], 0, 0, 0);
    acc[j] = __builtin_amdgcn_mfma_f32_16x16x32_bf16(af1, b1, acc[j], 0, 0, 0);
  }

  float bpv[4];
#pragma unroll
  for (int r = 0; r < 4; ++r) bpv[r] = bp[w * 16 + q * 4 + r];
  float* outb = dout + ((size_t)(b * 64) << 16) + p0;
#pragma unroll
  for (int r = 0; r < 4; ++r) {
    float* orow = outb + ((size_t)(w * 16 + q * 4 + r) << 16);
#pragma unroll
    for (int j = 0; j < 16; ++j) orow[j * 16 + cl] = acc[j][r] + bpv[r];
  }
}

extern "C" void kernel_launch(void* const* d_in, const int* in_sizes, int n_in,
                              void* d_out, int out_size, void* d_ws, size_t ws_size,
                              hipStream_t stream) {
  const float* x = (const float*)d_in[0];
  const float* w3 = (const float*)d_in[1];
  const float* b3 = (const float*)d_in[2];
  const float* w5 = (const float*)d_in[3];
  const float* b5 = (const float*)d_in[4];
  const float* wqkv = (const float*)d_in[5];
  const float* scale = (const float*)d_in[6];
  const float* g1w = (const float*)d_in[7];
  const float* g1b = (const float*)d_in[8];
  const float* g2w = (const float*)d_in[9];
  const float* g2b = (const float*)d_in[10];
  const float* wp = (const float*)d_in[11];
  const float* bp = (const float*)d_in[12];
  float* out = (float*)d_out;

  char* ws = (char*)d_ws;
  u16* qkv = (u16*)(ws);
  u16* ohb = (u16*)(ws + 100663296ull);
  u16* ovb = (u16*)(ws + 134217728ull);
  float* fs = (float*)(ws + 167772160ull);
  float* gxsum = fs;        // 256
  float* cwaw = fs + 256;   // 8
  float* rnorm = fs + 264;  // 512

  k_gx<<<256, 256, 0, stream>>>(x, gxsum);
  k_gate<<<1, 64, 0, stream>>>(gxsum, g1w, g1b, g2w, g2b, cwaw);
  k_qkv<<<2048, 256, 0, stream>>>(x, wqkv, qkv);
  k_rnorm<<<512, 256, 0, stream>>>(qkv, rnorm);
  k_conv<<<8192, 256, 0, stream>>>(x, w3, b3, w5, b5, cwaw, out);
  k_attn<<<2048, 256, 0, stream>>>(qkv, rnorm, scale, ohb, ovb);
  k_final<<<1024, 256, 0, stream>>>(out, ohb, ovb, wp, bp, cwaw);
}

// Round 7
// 338.425 us; speedup vs baseline: 1.2411x; 1.0490x over previous
//
#include <hip/hip_runtime.h>
#include <stdint.h>

// CAFormer fused block, MI355X gfx950.
// R10 (on R9=355us, k_attn 108us Mfma 12.7%):
//  - k_attn staged loops: raw s_barrier + lgkmcnt(0)-only (no vmcnt drain) and
//    register-preload of next window's global data -> HBM latency overlaps the
//    MFMA cluster (T14/T4). s_setprio(1) around MFMA (T5).
//  - k_conv: zero-padded [12][260] halo tile -> branch-free 3x3+5x5 loops.
// ws layout (160 MiB + 3088 B, proven):
//   qkv bf16 [4][192][65536] @ 0          (100663296 B)
//   oh  bf16 [4][64][65536]  @ 100663296  (33554432 B)
//   ov  bf16                 @ 134217728  (33554432 B)
//   f32 scratch @ 167772160: gxsum[256] cwaw[8] rnorm[512]

typedef unsigned short u16;
typedef __attribute__((ext_vector_type(8))) short bf16x8;
typedef __attribute__((ext_vector_type(4))) float f32x4;

#define DEV static __device__ __forceinline__

DEV u16 f2bf(float f) {
  unsigned u = __float_as_uint(f);
  return (u16)((u + 0x7fffu + ((u >> 16) & 1u)) >> 16);
}
DEV float bf2f(u16 h) { return __uint_as_float(((unsigned)h) << 16); }

// barrier that orders LDS only: lgkmcnt(0) + raw s_barrier. Global loads in
// flight (thread-private regs) are NOT drained, unlike __syncthreads().
DEV void bar_lds() {
  asm volatile("s_waitcnt lgkmcnt(0)" ::: "memory");
  __builtin_amdgcn_s_barrier();
}

// ---------------- gating: per-(b,c) spatial sum of x ----------------
__global__ void k_gx(const float* __restrict__ x, float* __restrict__ gxsum) {
  int bc = blockIdx.x, t = threadIdx.x;
  const float4* p = (const float4*)(x + ((size_t)bc << 16));
  float s = 0.f;
  for (int i = 0; i < 64; ++i) { float4 v = p[t + 256 * i]; s += v.x + v.y + v.z + v.w; }
  for (int off = 32; off; off >>= 1) s += __shfl_down(s, off);
  __shared__ float lds[4];
  if ((t & 63) == 0) lds[t >> 6] = s;
  __syncthreads();
  if (t == 0) gxsum[bc] = lds[0] + lds[1] + lds[2] + lds[3];
}

// ---------------- gating MLP -> cw/aw per batch ----------------
__global__ void k_gate(const float* __restrict__ gxsum, const float* __restrict__ g1w,
                       const float* __restrict__ g1b, const float* __restrict__ g2w,
                       const float* __restrict__ g2b, float* __restrict__ cwaw) {
  __shared__ float h1[4][16];
  int t = threadIdx.x;
  int b = t >> 4, j = t & 15;
  float a = g1b[j];
  for (int c = 0; c < 64; ++c) a += g1w[j * 64 + c] * gxsum[b * 64 + c] * (1.f / 65536.f);
  h1[b][j] = fmaxf(a, 0.f);
  __syncthreads();
  if (t < 4) {
    float l0 = g2b[0], l1 = g2b[1];
    for (int k = 0; k < 16; ++k) { l0 += g2w[k] * h1[t][k]; l1 += g2w[16 + k] * h1[t][k]; }
    float m = fmaxf(l0, l1);
    float e0 = __expf(l0 - m), e1 = __expf(l1 - m);
    float inv = 1.f / (e0 + e1);
    cwaw[t * 2 + 0] = e0 * inv;  // conv weight
    cwaw[t * 2 + 1] = e1 * inv;  // attn weight
  }
}

// ---------------- qkv projection as MFMA GEMM: [192x64] x [64x128px] ----------------
__global__ __launch_bounds__(256) void k_qkv(const float* __restrict__ x,
                                             const float* __restrict__ wqkv,
                                             u16* __restrict__ qkv) {
  __shared__ u16 Ws[192 * 72];  // A: [row][ch], stride 72 shorts
  __shared__ u16 Xs[128 * 72];  // B^T: [px][ch]
  int t = threadIdx.x;
  int b = blockIdx.x >> 9;
  int p0 = (blockIdx.x & 511) << 7;

  // stage wqkv (192x64 fp32 -> bf16)
  {
    int row = t >> 2, c0 = (t & 3) << 4;
#pragma unroll
    for (int i = 0; i < 3; ++i) {
      int r = i * 64 + row;
      const float* src = wqkv + r * 64 + c0;
      unsigned pk[8];
#pragma unroll
      for (int j = 0; j < 8; ++j)
        pk[j] = (unsigned)f2bf(src[2 * j]) | ((unsigned)f2bf(src[2 * j + 1]) << 16);
      uint4* dst = (uint4*)&Ws[r * 72 + c0];
      dst[0] = make_uint4(pk[0], pk[1], pk[2], pk[3]);
      dst[1] = make_uint4(pk[4], pk[5], pk[6], pk[7]);
    }
  }
  // stage x tile: 64ch x 128px, transposed -> Xs[px][ch]
  {
    int p = t & 127, ch = t >> 7;
    const float* xb = x + ((size_t)(b * 64) << 16) + p0 + p;
#pragma unroll
    for (int i = 0; i < 32; ++i) {
      int c = 2 * i + ch;
      Xs[p * 72 + c] = f2bf(xb[(size_t)c << 16]);
    }
  }
  __syncthreads();

  int w = t >> 6, l = t & 63, q = l >> 4, cl = l & 15;
  bf16x8 af[3][2];
#pragma unroll
  for (int g = 0; g < 3; ++g)
#pragma unroll
    for (int k = 0; k < 2; ++k)
      af[g][k] = *(const bf16x8*)&Ws[(w * 48 + g * 16 + cl) * 72 + k * 32 + q * 8];

  f32x4 acc[3][8];
  f32x4 zero = {0.f, 0.f, 0.f, 0.f};
#pragma unroll
  for (int g = 0; g < 3; ++g)
#pragma unroll
    for (int j = 0; j < 8; ++j) acc[g][j] = zero;

  for (int j = 0; j < 8; ++j) {
    bf16x8 b0 = *(const bf16x8*)&Xs[(j * 16 + cl) * 72 + q * 8];
    bf16x8 b1 = *(const bf16x8*)&Xs[(j * 16 + cl) * 72 + 32 + q * 8];
#pragma unroll
    for (int g = 0; g < 3; ++g) {
      acc[g][j] = __builtin_amdgcn_mfma_f32_16x16x32_bf16(af[g][0], b0, acc[g][j], 0, 0, 0);
      acc[g][j] = __builtin_amdgcn_mfma_f32_16x16x32_bf16(af[g][1], b1, acc[g][j], 0, 0, 0);
    }
  }
  u16* outb = qkv + ((size_t)(b * 192) << 16) + p0;
  for (int g = 0; g < 3; ++g) {
    int rowb = w * 48 + g * 16 + q * 4;
#pragma unroll
    for (int r = 0; r < 4; ++r) {
      u16* orow = outb + ((size_t)(rowb + r) << 16);
#pragma unroll
      for (int j = 0; j < 8; ++j) orow[j * 16 + cl] = f2bf(acc[g][j][r]);
    }
  }
}

// ---------------- 1/||plane|| for q,k channels (from bf16 qkv) ----------------
__global__ void k_rnorm(const u16* __restrict__ qkv, float* __restrict__ rnorm) {
  int b = blockIdx.x >> 7, ch = blockIdx.x & 127;
  const uint2* p2 = (const uint2*)(qkv + ((size_t)(b * 192 + ch) << 16));
  int t = threadIdx.x;
  float s = 0.f;
  for (int i = 0; i < 64; ++i) {
    uint2 v = p2[t + 256 * i];
    float a = bf2f(v.x & 0xffff), bq = bf2f(v.x >> 16);
    float c = bf2f(v.y & 0xffff), d = bf2f(v.y >> 16);
    s += a * a + bq * bq + c * c + d * d;
  }
  for (int off = 32; off; off >>= 1) s += __shfl_down(s, off);
  __shared__ float lds[4];
  if ((t & 63) == 0) lds[t >> 6] = s;
  __syncthreads();
  if (t == 0) {
    float tot = lds[0] + lds[1] + lds[2] + lds[3];
    rnorm[blockIdx.x] = 1.f / fmaxf(sqrtf(tot), 1e-12f);
  }
}

// ---------------- depthwise 3x3+5x5 conv, branch-free padded tile ----------------
__global__ void k_conv(const float* __restrict__ x, const float* __restrict__ w3,
                       const float* __restrict__ b3, const float* __restrict__ w5,
                       const float* __restrict__ b5, const float* __restrict__ cwaw,
                       float* __restrict__ outmix) {
  int rt = blockIdx.x & 31, bc = blockIdx.x >> 5, c = bc & 63, b = bc >> 6;
  int r0 = rt * 8;
  const float* xp = x + ((size_t)bc << 16);
  __shared__ float xs[12][260];  // padded: col g maps to index g+2; 0..1,258..259 zero
  int y = threadIdx.x;
  for (int rr = 0; rr < 12; ++rr) {
    int gr = r0 - 2 + rr;
    xs[rr][y + 2] = (gr >= 0 && gr < 256) ? xp[(size_t)gr * 256 + y] : 0.f;
  }
  if (y < 2) {
    for (int rr = 0; rr < 12; ++rr) { xs[rr][y] = 0.f; xs[rr][258 + y] = 0.f; }
  }
  __syncthreads();
  float W3[9], W5[25];
#pragma unroll
  for (int i = 0; i < 9; ++i) W3[i] = w3[c * 9 + i];
#pragma unroll
  for (int i = 0; i < 25; ++i) W5[i] = w5[c * 25 + i];
  float bias = b3[c] + b5[c];
  float cw = cwaw[b * 2];
  float* op = outmix + ((size_t)bc << 16);
  for (int k = 0; k < 8; ++k) {
    float a = bias;
#pragma unroll
    for (int di = 0; di < 3; ++di)
#pragma unroll
      for (int dj = 0; dj < 3; ++dj)
        a += W3[di * 3 + dj] * xs[k + 1 + di][y + 1 + dj];
#pragma unroll
    for (int di = 0; di < 5; ++di)
#pragma unroll
      for (int dj = 0; dj < 5; ++dj)
        a += W5[di * 5 + dj] * xs[k + di][y + dj];
    op[(size_t)(r0 + k) * 256 + y] = cw * a;
  }
}

// ---------------- axial attention, MFMA bf16, 64-row tiles, pipelined staging ----------------
// dir0: S direct (native Q,K rows); PV stages V^T per z-window (preloaded regs).
// dir1: S stages Q^T + K^T per y-window (preloaded regs); PV direct.
__global__ __launch_bounds__(256) void k_attn(
    const u16* __restrict__ qkv, const float* __restrict__ rnorm,
    const float* __restrict__ scale, u16* __restrict__ oh, u16* __restrict__ ov) {
  __shared__ __align__(16) unsigned char smem[54272];
  u16* Pls = (u16*)smem;                       // [64][264] bf16 (33792 B)
  unsigned* Qt32 = (unsigned*)smem;            // [64][20] u32 (5120 B; dir1 S, Pls dead)
  float* red = (float*)(smem + 33792);         // [4][64] f32
  unsigned* Tt32 = (unsigned*)(smem + 33792);  // [256][20] u32 (Kt dir1-S / Vt dir0-PV)
  float* Osf = (float*)smem;                   // [32][260] f32 (dir1 store; Pls dead)

  int t = threadIdx.x;
  int w = t >> 6, l = t & 63, q = l >> 4, cl = l & 15;
  // XCD-aware bijective swizzle: one channel's 8 blocks (4 rt x 2 dir) are
  // consecutive in idx -> same XCD -> planes shared in that XCD's L2.
  int idx = (blockIdx.x & 7) * 256 + (blockIdx.x >> 3);
  int rt = idx & 3, dir = (idx >> 2) & 1, c = (idx >> 3) & 63, b = idx >> 9;
  int r0 = rt << 6;

  const size_t P = 65536;
  const u16* Qp = qkv + (size_t)(b * 192 + c) * P;
  const u16* Kp = qkv + (size_t)(b * 192 + 64 + c) * P;
  const u16* Vp = qkv + (size_t)(b * 192 + 128 + c) * P;

  float sc = rnorm[b * 128 + c] * rnorm[b * 128 + 64 + c] * scale[c >> 3];

  f32x4 Sa[4][4];
  f32x4 zero = {0.f, 0.f, 0.f, 0.f};
#pragma unroll
  for (int i = 0; i < 4; ++i)
#pragma unroll
    for (int j = 0; j < 4; ++j) Sa[i][j] = zero;

  // ---- S phase: 8 k-windows of 32 ----
  if (dir == 0) {
    for (int yw = 0; yw < 8; ++yw) {
      int y0 = yw << 5;
      bf16x8 af[4], bfr[4];
#pragma unroll
      for (int i = 0; i < 4; ++i)
        af[i] = *(const bf16x8*)&Qp[(size_t)(r0 + i * 16 + cl) * 256 + y0 + q * 8];
#pragma unroll
      for (int j = 0; j < 4; ++j)
        bfr[j] = *(const bf16x8*)&Kp[(size_t)(w * 64 + j * 16 + cl) * 256 + y0 + q * 8];
      __builtin_amdgcn_s_setprio(1);
#pragma unroll
      for (int i = 0; i < 4; ++i)
#pragma unroll
        for (int j = 0; j < 4; ++j)
          Sa[i][j] = __builtin_amdgcn_mfma_f32_16x16x32_bf16(af[i], bfr[j], Sa[i][j], 0, 0, 0);
      __builtin_amdgcn_s_setprio(0);
    }
  } else {
    // stage K^T (256 cols) + Q^T (64 cols at r0) per window; next window's
    // global loads preloaded into regs so they fly during the MFMA cluster.
    int y2 = t >> 4, colc = t & 15;
    int kkey = (((y2 >> 2) ^ (colc & 3)) << 2) + (y2 & 3);
    int qkey = (((y2 >> 2) ^ ((colc >> 2) & 3)) << 2) + (y2 & 3);
    unsigned KA[8], KB[8], QA[2], QB[2];
    {
      const u16* krp = Kp + (size_t)(2 * y2) * 256 + colc * 16;
      uint4 ka0 = *(const uint4*)krp;
      uint4 ka1 = *(const uint4*)(krp + 8);
      uint4 kb0 = *(const uint4*)(krp + 256);
      uint4 kb1 = *(const uint4*)(krp + 264);
      const u16* qrp = Qp + (size_t)(2 * y2) * 256 + r0 + colc * 4;
      uint2 qa = *(const uint2*)qrp;
      uint2 qb = *(const uint2*)(qrp + 256);
      KA[0] = ka0.x; KA[1] = ka0.y; KA[2] = ka0.z; KA[3] = ka0.w;
      KA[4] = ka1.x; KA[5] = ka1.y; KA[6] = ka1.z; KA[7] = ka1.w;
      KB[0] = kb0.x; KB[1] = kb0.y; KB[2] = kb0.z; KB[3] = kb0.w;
      KB[4] = kb1.x; KB[5] = kb1.y; KB[6] = kb1.z; KB[7] = kb1.w;
      QA[0] = qa.x; QA[1] = qa.y; QB[0] = qb.x; QB[1] = qb.y;
    }
#pragma unroll
    for (int yw = 0; yw < 8; ++yw) {
      bar_lds();  // prior window's LDS reads complete
#pragma unroll
      for (int m = 0; m < 16; ++m) {
        unsigned lo = (m & 1) ? (KA[m >> 1] >> 16) : (KA[m >> 1] & 0xffffu);
        unsigned hi = (m & 1) ? (KB[m >> 1] & 0xffff0000u) : (KB[m >> 1] << 16);
        Tt32[(colc * 16 + m) * 20 + kkey] = lo | hi;
      }
#pragma unroll
      for (int m = 0; m < 4; ++m) {
        unsigned lo = (m & 1) ? (QA[m >> 1] >> 16) : (QA[m >> 1] & 0xffffu);
        unsigned hi = (m & 1) ? (QB[m >> 1] & 0xffff0000u) : (QB[m >> 1] << 16);
        Qt32[(colc * 4 + m) * 20 + qkey] = lo | hi;
      }
      unsigned NKA[8], NKB[8], NQA[2], NQB[2];
      if (yw < 7) {
        int y0 = (yw + 1) << 5;
        const u16* krp = Kp + (size_t)(y0 + 2 * y2) * 256 + colc * 16;
        uint4 ka0 = *(const uint4*)krp;
        uint4 ka1 = *(const uint4*)(krp + 8);
        uint4 kb0 = *(const uint4*)(krp + 256);
        uint4 kb1 = *(const uint4*)(krp + 264);
        const u16* qrp = Qp + (size_t)(y0 + 2 * y2) * 256 + r0 + colc * 4;
        uint2 qa = *(const uint2*)qrp;
        uint2 qb = *(const uint2*)(qrp + 256);
        NKA[0] = ka0.x; NKA[1] = ka0.y; NKA[2] = ka0.z; NKA[3] = ka0.w;
        NKA[4] = ka1.x; NKA[5] = ka1.y; NKA[6] = ka1.z; NKA[7] = ka1.w;
        NKB[0] = kb0.x; NKB[1] = kb0.y; NKB[2] = kb0.z; NKB[3] = kb0.w;
        NKB[4] = kb1.x; NKB[5] = kb1.y; NKB[6] = kb1.z; NKB[7] = kb1.w;
        NQA[0] = qa.x; NQA[1] = qa.y; NQB[0] = qb.x; NQB[1] = qb.y;
      }
      bar_lds();  // staged data visible; next-window loads stay in flight
      bf16x8 af[4], bfr[4];
#pragma unroll
      for (int i = 0; i < 4; ++i)
        af[i] = *(const bf16x8*)&Qt32[(i * 16 + cl) * 20 + ((q ^ i) << 2)];
#pragma unroll
      for (int j = 0; j < 4; ++j) {
        int col = w * 64 + j * 16 + cl;
        bfr[j] = *(const bf16x8*)&Tt32[col * 20 + ((q ^ j) << 2)];
      }
      __builtin_amdgcn_s_setprio(1);
#pragma unroll
      for (int i = 0; i < 4; ++i)
#pragma unroll
        for (int j = 0; j < 4; ++j)
          Sa[i][j] = __builtin_amdgcn_mfma_f32_16x16x32_bf16(af[i], bfr[j], Sa[i][j], 0, 0, 0);
      __builtin_amdgcn_s_setprio(0);
      if (yw < 7) {
#pragma unroll
        for (int m = 0; m < 8; ++m) { KA[m] = NKA[m]; KB[m] = NKB[m]; }
        QA[0] = NQA[0]; QA[1] = NQA[1]; QB[0] = NQB[0]; QB[1] = NQB[1];
      }
    }
    __syncthreads();  // close Qt32/Tt32 reads before red/Pls writes
  }

  // ---- softmax over cols, NO max pass: |S*sc| <= scale ----
  float sm[4][4];
#pragma unroll
  for (int i = 0; i < 4; ++i)
#pragma unroll
    for (int r = 0; r < 4; ++r) {
      float s0 = 0.f;
#pragma unroll
      for (int j = 0; j < 4; ++j) {
        float e = __expf(Sa[i][j][r] * sc);
        Sa[i][j][r] = e;
        s0 += e;
      }
#pragma unroll
      for (int off = 1; off < 16; off <<= 1) s0 += __shfl_xor(s0, off);
      sm[i][r] = s0;
    }
  if (cl == 0) {
#pragma unroll
    for (int i = 0; i < 4; ++i)
#pragma unroll
      for (int r = 0; r < 4; ++r) red[w * 64 + i * 16 + q * 4 + r] = sm[i][r];
  }
  __syncthreads();
#pragma unroll
  for (int i = 0; i < 4; ++i)
#pragma unroll
    for (int r = 0; r < 4; ++r) {
      int rho = i * 16 + q * 4 + r;
      sm[i][r] = 1.f / (red[rho] + red[64 + rho] + red[128 + rho] + red[192 + rho]);
    }
  // P -> Pls row-major [row][z]
#pragma unroll
  for (int i = 0; i < 4; ++i)
#pragma unroll
    for (int r = 0; r < 4; ++r) {
      int rho = i * 16 + q * 4 + r;
#pragma unroll
      for (int j = 0; j < 4; ++j)
        Pls[rho * 264 + w * 64 + j * 16 + cl] = f2bf(Sa[i][j][r] * sm[i][r]);
    }
  __syncthreads();

  // ---- O = P V over 8 z-windows ----
  f32x4 Oa[4][4];
#pragma unroll
  for (int i = 0; i < 4; ++i)
#pragma unroll
    for (int j = 0; j < 4; ++j) Oa[i][j] = zero;

  if (dir == 0) {
    // stage V^T per window, next window's loads preloaded into regs.
    int z2 = t >> 4, colc = t & 15;
    int zlo = z2 & 3;
    int wkey = (((z2 >> 2) ^ (colc & 3)) << 2) + zlo;
    unsigned A[8], Bv[8];
    {
      const u16* rp = Vp + (size_t)(2 * z2) * 256 + colc * 16;
      uint4 a0 = *(const uint4*)rp;
      uint4 a1 = *(const uint4*)(rp + 8);
      uint4 c0 = *(const uint4*)(rp + 256);
      uint4 c1 = *(const uint4*)(rp + 264);
      A[0] = a0.x; A[1] = a0.y; A[2] = a0.z; A[3] = a0.w;
      A[4] = a1.x; A[5] = a1.y; A[6] = a1.z; A[7] = a1.w;
      Bv[0] = c0.x; Bv[1] = c0.y; Bv[2] = c0.z; Bv[3] = c0.w;
      Bv[4] = c1.x; Bv[5] = c1.y; Bv[6] = c1.z; Bv[7] = c1.w;
    }
#pragma unroll
    for (int zw = 0; zw < 8; ++zw) {
      int z0 = zw << 5;
      bar_lds();  // previous window's Vt reads complete
#pragma unroll
      for (int m = 0; m < 16; ++m) {
        unsigned lo = (m & 1) ? (A[m >> 1] >> 16) : (A[m >> 1] & 0xffffu);
        unsigned hi = (m & 1) ? (Bv[m >> 1] & 0xffff0000u) : (Bv[m >> 1] << 16);
        Tt32[(colc * 16 + m) * 20 + wkey] = lo | hi;
      }
      unsigned NA[8], NBv[8];
      if (zw < 7) {
        const u16* rp = Vp + (size_t)(z0 + 32 + 2 * z2) * 256 + colc * 16;
        uint4 a0 = *(const uint4*)rp;
        uint4 a1 = *(const uint4*)(rp + 8);
        uint4 c0 = *(const uint4*)(rp + 256);
        uint4 c1 = *(const uint4*)(rp + 264);
        NA[0] = a0.x; NA[1] = a0.y; NA[2] = a0.z; NA[3] = a0.w;
        NA[4] = a1.x; NA[5] = a1.y; NA[6] = a1.z; NA[7] = a1.w;
        NBv[0] = c0.x; NBv[1] = c0.y; NBv[2] = c0.z; NBv[3] = c0.w;
        NBv[4] = c1.x; NBv[5] = c1.y; NBv[6] = c1.z; NBv[7] = c1.w;
      }
      bar_lds();  // staged data visible; next-window loads stay in flight
      bf16x8 af[4], bfr[4];
#pragma unroll
      for (int i = 0; i < 4; ++i)
        af[i] = *(const bf16x8*)&Pls[(i * 16 + cl) * 264 + z0 + q * 8];
#pragma unroll
      for (int j = 0; j < 4; ++j) {
        int col = w * 64 + j * 16 + cl;
        bfr[j] = *(const bf16x8*)&Tt32[col * 20 + ((q ^ j) << 2)];
      }
      __builtin_amdgcn_s_setprio(1);
#pragma unroll
      for (int i = 0; i < 4; ++i)
#pragma unroll
        for (int j = 0; j < 4; ++j)
          Oa[i][j] = __builtin_amdgcn_mfma_f32_16x16x32_bf16(af[i], bfr[j], Oa[i][j], 0, 0, 0);
      __builtin_amdgcn_s_setprio(0);
      if (zw < 7) {
#pragma unroll
        for (int m = 0; m < 8; ++m) { A[m] = NA[m]; Bv[m] = NBv[m]; }
      }
    }
    u16* op = oh + (size_t)(b * 64 + c) * P;
#pragma unroll
    for (int i = 0; i < 4; ++i)
#pragma unroll
      for (int j = 0; j < 4; ++j)
#pragma unroll
        for (int r = 0; r < 4; ++r)
          op[(size_t)(r0 + i * 16 + q * 4 + r) * 256 + w * 64 + j * 16 + cl] = f2bf(Oa[i][j][r]);
  } else {
    for (int zw = 0; zw < 8; ++zw) {
      int z0 = zw << 5;
      bf16x8 af[4], bfr[4];
#pragma unroll
      for (int i = 0; i < 4; ++i)
        af[i] = *(const bf16x8*)&Pls[(i * 16 + cl) * 264 + z0 + q * 8];
#pragma unroll
      for (int j = 0; j < 4; ++j)
        bfr[j] = *(const bf16x8*)&Vp[(size_t)(w * 64 + j * 16 + cl) * 256 + z0 + q * 8];
      __builtin_amdgcn_s_setprio(1);
#pragma unroll
      for (int i = 0; i < 4; ++i)
#pragma unroll
        for (int j = 0; j < 4; ++j)
          Oa[i][j] = __builtin_amdgcn_mfma_f32_16x16x32_bf16(af[i], bfr[j], Oa[i][j], 0, 0, 0);
      __builtin_amdgcn_s_setprio(0);
    }
    // transposed store via LDS (Pls dead; barrier-protected)
    u16* op = ov + (size_t)(b * 64 + c) * P;
    __syncthreads();
    for (int h = 0; h < 2; ++h) {
#pragma unroll
      for (int ii = 0; ii < 2; ++ii) {
        int i = h * 2 + ii;
#pragma unroll
        for (int j = 0; j < 4; ++j)
#pragma unroll
          for (int r = 0; r < 4; ++r)
            Osf[(ii * 16 + q * 4 + r) * 260 + w * 64 + j * 16 + cl] = Oa[i][j][r];
      }
      __syncthreads();
      int rr = t & 31, xb = t >> 5;
      for (int xx = 0; xx < 32; ++xx) {
        int xcol = xx * 8 + xb;
        op[(size_t)xcol * 256 + r0 + h * 32 + rr] = f2bf(Osf[rr * 260 + xcol]);
      }
      __syncthreads();
    }
  }
}

// ---------------- mix + 64x64 projection as MFMA GEMM, in place on d_out ----------------
__global__ __launch_bounds__(256) void k_final(
    float* __restrict__ dout, const u16* __restrict__ oh, const u16* __restrict__ ov,
    const float* __restrict__ wp, const float* __restrict__ bp,
    const float* __restrict__ cwaw) {
  __shared__ u16 Ms[256 * 72];  // B^T: [px][ch]
  __shared__ u16 Ws[64 * 72];   // A: [row][ch]
  int t = threadIdx.x;
  int b = blockIdx.x >> 8;
  int p0 = (blockIdx.x & 255) << 8;
  float aw = cwaw[b * 2 + 1];

  {
    int row = t >> 2, c0 = (t & 3) << 4;
    const float* src = wp + row * 64 + c0;
    unsigned pk[8];
#pragma unroll
    for (int j = 0; j < 8; ++j)
      pk[j] = (unsigned)f2bf(src[2 * j]) | ((unsigned)f2bf(src[2 * j + 1]) << 16);
    uint4* dst = (uint4*)&Ws[row * 72 + c0];
    dst[0] = make_uint4(pk[0], pk[1], pk[2], pk[3]);
    dst[1] = make_uint4(pk[4], pk[5], pk[6], pk[7]);
  }
  {
    size_t base = ((size_t)(b * 64) << 16) + p0 + t;
    for (int c = 0; c < 64; ++c) {
      size_t off = base + ((size_t)c << 16);
      float m = dout[off] + aw * (bf2f(oh[off]) + bf2f(ov[off]));
      Ms[t * 72 + c] = f2bf(m);
    }
  }
  __syncthreads();

  int w = t >> 6, l = t & 63, q = l >> 4, cl = l & 15;
  bf16x8 af0 = *(const bf16x8*)&Ws[(w * 16 + cl) * 72 + q * 8];
  bf16x8 af1 = *(const bf16x8*)&Ws[(w * 16 + cl) * 72 + 32 + q * 8];

  f32x4 acc[16];
  f32x4 zero = {0.f, 0.f, 0.f, 0.f};
#pragma unroll
  for (int j = 0; j < 16; ++j) acc[j] = zero;

  for (int j = 0; j < 16; ++j) {
    bf16x8 b0 = *(const bf16x8*)&Ms[(j * 16 + cl) * 72 + q * 8];
    bf16x8 b1 = *(const bf16x8*)&Ms[(j * 16 + cl) * 72 + 32 + q * 8];
    acc[j] = __builtin_amdgcn_mfma_f32_16x16x32_bf16(af0, b0, acc[j], 0, 0, 0);
    acc[j] = __builtin_amdgcn_mfma_f32_16x16x32_bf16(af1, b1, acc[j], 0, 0, 0);
  }

  float bpv[4];
#pragma unroll
  for (int r = 0; r < 4; ++r) bpv[r] = bp[w * 16 + q * 4 + r];
  float* outb = dout + ((size_t)(b * 64) << 16) + p0;
#pragma unroll
  for (int r = 0; r < 4; ++r) {
    float* orow = outb + ((size_t)(w * 16 + q * 4 + r) << 16);
#pragma unroll
    for (int j = 0; j < 16; ++j) orow[j * 16 + cl] = acc[j][r] + bpv[r];
  }
}

extern "C" void kernel_launch(void* const* d_in, const int* in_sizes, int n_in,
                              void* d_out, int out_size, void* d_ws, size_t ws_size,
                              hipStream_t stream) {
  const float* x = (const float*)d_in[0];
  const float* w3 = (const float*)d_in[1];
  const float* b3 = (const float*)d_in[2];
  const float* w5 = (const float*)d_in[3];
  const float* b5 = (const float*)d_in[4];
  const float* wqkv = (const float*)d_in[5];
  const float* scale = (const float*)d_in[6];
  const float* g1w = (const float*)d_in[7];
  const float* g1b = (const float*)d_in[8];
  const float* g2w = (const float*)d_in[9];
  const float* g2b = (const float*)d_in[10];
  const float* wp = (const float*)d_in[11];
  const float* bp = (const float*)d_in[12];
  float* out = (float*)d_out;

  char* ws = (char*)d_ws;
  u16* qkv = (u16*)(ws);
  u16* ohb = (u16*)(ws + 100663296ull);
  u16* ovb = (u16*)(ws + 134217728ull);
  float* fs = (float*)(ws + 167772160ull);
  float* gxsum = fs;        // 256
  float* cwaw = fs + 256;   // 8
  float* rnorm = fs + 264;  // 512

  k_gx<<<256, 256, 0, stream>>>(x, gxsum);
  k_gate<<<1, 64, 0, stream>>>(gxsum, g1w, g1b, g2w, g2b, cwaw);
  k_qkv<<<2048, 256, 0, stream>>>(x, wqkv, qkv);
  k_rnorm<<<512, 256, 0, stream>>>(qkv, rnorm);
  k_conv<<<8192, 256, 0, stream>>>(x, w3, b3, w5, b5, cwaw, out);
  k_attn<<<2048, 256, 0, stream>>>(qkv, rnorm, scale, ohb, ovb);
  k_final<<<1024, 256, 0, stream>>>(out, ohb, ovb, wp, bp, cwaw);
}